// Round 4
// baseline (391.441 us; speedup 1.0000x reference)
//
#include <hip/hip_runtime.h>
#include <hip/hip_bf16.h>
#include <math.h>

#define S_LEN 2048
#define NBATCH 32
#define DIM 384
#define NTOK (NBATCH * S_LEN)

typedef __hip_bfloat16 bf16;
typedef __attribute__((ext_vector_type(8))) short short8v;
typedef __attribute__((ext_vector_type(4))) float f32x4;
typedef __attribute__((ext_vector_type(2))) unsigned int uint2v;
typedef __attribute__((ext_vector_type(4))) int int4v;
typedef short8v fragT;

#define LDAP 72   // padded LDS leading dim (halfwords) for 64-wide tiles
#define APAD 392  // padded leading dim for persistent A (384 + 8)

__device__ __forceinline__ float bf2f(unsigned short u) {
  union { unsigned int i; float f; } c; c.i = ((unsigned int)u) << 16; return c.f;
}

// ---------------- weight fp32 -> bf16 conversion ----------------
__global__ __launch_bounds__(256) void conv_kernel(const float* __restrict__ we,
                                                   const float* __restrict__ wp,
                                                   bf16* __restrict__ web,
                                                   bf16* __restrict__ wpb) {
  int i = blockIdx.x * 256 + threadIdx.x;
  int stride = gridDim.x * 256;
  for (int j = i; j < 1632 * 384; j += stride) web[j] = __float2bfloat16(we[j]);
  for (int j = i; j < 384 * 768; j += stride) wpb[j] = __float2bfloat16(wp[j]);
}

// ---------------- LayerNorm: x (fp32) -> xn (bf16) ----------------
__global__ __launch_bounds__(256) void ln_kernel(const float* __restrict__ x,
                                                 const float* __restrict__ nw,
                                                 bf16* __restrict__ xn) {
  int token = blockIdx.x * 4 + (threadIdx.x >> 6);
  int lane = threadIdx.x & 63;
  const float* xr = x + (size_t)token * DIM;
  float v[6];
  float s = 0.f, sq = 0.f;
#pragma unroll
  for (int j = 0; j < 6; ++j) {
    v[j] = xr[lane + j * 64];
    s += v[j];
    sq += v[j] * v[j];
  }
#pragma unroll
  for (int o = 32; o; o >>= 1) {
    s += __shfl_xor(s, o);
    sq += __shfl_xor(sq, o);
  }
  float mu = s * (1.f / DIM);
  float var = sq * (1.f / DIM) - mu * mu;
  float rs = rsqrtf(var + 1e-5f);
  bf16* xo = xn + (size_t)token * DIM;
#pragma unroll
  for (int j = 0; j < 6; ++j) {
    int c = lane + j * 64;
    xo[c] = __float2bfloat16((v[j] - mu) * rs * nw[c]);
  }
}

// ---------------- persistent-A expand GEMM (MFMA) + GEGLU epilogue ----------------
// One block per 128 tokens. Full-K A tile (128x384, 98 KB) staged in LDS ONCE;
// loop over all 13 N-tiles (y=0: qk 96 cols; y=1..12: 64 lin + 64 matching pre
// cols, remapped so frag ni and ni+2 pair lin/pre). B streams through a
// double-buffered LDS chunk, reg-staged, ONE barrier per K-step.
__global__ __launch_bounds__(256, 1) void expand_persist_kernel(
    const bf16* __restrict__ xn, const bf16* __restrict__ web,
    bf16* __restrict__ qkb, bf16* __restrict__ gl, bf16* __restrict__ gv) {
  __shared__ short As[128 * APAD];      // 100352 B
  __shared__ short Bs[2][128 * LDAP];   // 36864 B
  int t = threadIdx.x;
  int lane = t & 63, w = t >> 6;
  int wr = w >> 1, wc = w & 1;
  int row0 = blockIdx.x * 128;
  int m = lane & 15, g = lane >> 4;

  // B global row for chunk row r of tile y
  auto brow_of = [&](int y, int r) -> int {
    if (y == 0) return r;
    int half = r >> 6, nn = r & 63;
    return (nn < 32) ? (96 + (y - 1) * 64 + half * 32 + nn)
                     : (864 + (y - 1) * 64 + half * 32 + (nn - 32));
  };
  auto loadB = [&](int y, int kt, short8v* br) {
#pragma unroll
    for (int i = 0; i < 4; ++i) {
      int idx = i * 256 + t;  // 0..1023
      int r = idx >> 3, c16 = idx & 7;
      br[i] = *reinterpret_cast<const short8v*>(
          web + (size_t)brow_of(y, r) * 384 + kt * 64 + c16 * 8);
    }
  };
  auto writeB = [&](int p, const short8v* br) {
#pragma unroll
    for (int i = 0; i < 4; ++i) {
      int idx = i * 256 + t;
      int r = idx >> 3, c16 = idx & 7;
      *reinterpret_cast<short8v*>(&Bs[p][r * LDAP + c16 * 8]) = br[i];
    }
  };

  short8v brg[4];
  loadB(0, 0, brg);  // B(0) in flight during A staging

  // ---- stage A once: 128 x 384 bf16 -> As padded ----
#pragma unroll
  for (int c0 = 0; c0 < 24; c0 += 6) {
    short8v tmp[6];
#pragma unroll
    for (int i = 0; i < 6; ++i) {
      int idx = (c0 + i) * 256 + t;  // 0..6143
      int r = idx / 48, cc = (idx % 48) * 8;
      tmp[i] = *reinterpret_cast<const short8v*>(xn + (size_t)(row0 + r) * 384 + cc);
    }
#pragma unroll
    for (int i = 0; i < 6; ++i) {
      int idx = (c0 + i) * 256 + t;
      int r = idx / 48, cc = (idx % 48) * 8;
      *reinterpret_cast<short8v*>(&As[r * APAD + cc]) = tmp[i];
    }
  }

  f32x4 acc[4][4];
#pragma unroll
  for (int i = 0; i < 4; ++i)
#pragma unroll
    for (int j = 0; j < 4; ++j) acc[i][j] = (f32x4){0.f, 0.f, 0.f, 0.f};

  int y = 0, kt = 0;
  for (int s = 0; s < 78; ++s) {
    int p = s & 1;
    writeB(p, brg);  // waits (vmcnt) on B(s) loads issued one step ago
    int ny = y, nkt = kt + 1;
    if (nkt == 6) { nkt = 0; ny = y + 1; }
    if (s + 1 < 78) loadB(ny, nkt, brg);  // issue B(s+1), lands during compute
    __syncthreads();                      // Bs[p] (and As on s=0) visible

    // ---- compute: acc += A(:, kt*64..) x B-chunk ----
#pragma unroll
    for (int ks = 0; ks < 2; ++ks) {
      int ko = kt * 64 + ks * 32 + g * 8;
      fragT af[4], bfv[4];
#pragma unroll
      for (int mi = 0; mi < 4; ++mi)
        af[mi] = *reinterpret_cast<const fragT*>(&As[(wr * 64 + mi * 16 + m) * APAD + ko]);
#pragma unroll
      for (int ni = 0; ni < 4; ++ni)
        bfv[ni] = *reinterpret_cast<const fragT*>(&Bs[p][(wc * 64 + ni * 16 + m) * LDAP + ks * 32 + g * 8]);
#pragma unroll
      for (int mi = 0; mi < 4; ++mi)
#pragma unroll
        for (int ni = 0; ni < 4; ++ni)
          acc[mi][ni] = __builtin_amdgcn_mfma_f32_16x16x32_bf16(af[mi], bfv[ni], acc[mi][ni], 0, 0, 0);
    }

    if (kt == 5) {
      // ---- per-y epilogue (registers + global stores only) ----
      int cl = m, rg = g;
      if (y == 0) {
#pragma unroll
        for (int mi = 0; mi < 4; ++mi)
#pragma unroll
          for (int ni = 0; ni < 4; ++ni) {
            int n = wc * 64 + ni * 16 + cl;
            if (n < 96) {
#pragma unroll
              for (int r = 0; r < 4; ++r) {
                int token = row0 + wr * 64 + mi * 16 + rg * 4 + r;
                qkb[(size_t)token * 96 + n] = __float2bfloat16(acc[mi][ni][r]);
              }
            }
          }
      } else {
#pragma unroll
        for (int mi = 0; mi < 4; ++mi)
#pragma unroll
          for (int ni = 0; ni < 2; ++ni) {
            int c = (y - 1) * 64 + wc * 32 + ni * 16 + cl;
#pragma unroll
            for (int r = 0; r < 4; ++r) {
              int token = row0 + wr * 64 + mi * 16 + rg * 4 + r;
              float lin = acc[mi][ni][r];
              float pre = acc[mi][ni + 2][r];
              // gelu via tanh-exp form: 0.5*(1+tanh(z)) == 1/(1+e^{-2z})
              float z = 0.79788456f * (pre + 0.044715f * pre * pre * pre);
              float gelu = pre * (1.f / (1.f + __expf(-2.f * z)));
              float gval = lin * gelu;
              if (c < 384)
                gl[(size_t)token * DIM + c] = __float2bfloat16(gval);
              else
                gv[(size_t)token * DIM + (c - 384)] = __float2bfloat16(gval);
            }
          }
      }
#pragma unroll
      for (int i = 0; i < 4; ++i)
#pragma unroll
        for (int j = 0; j < 4; ++j) acc[i][j] = (f32x4){0.f, 0.f, 0.f, 0.f};
    }
    kt = nkt;
    y = ny;
  }
}

// ---------------- MFMA windowed causal attention ----------------
#define ATT_P_OFF 0
#define ATT_Q_OFF 8704
#define ATT_K_OFF 13312
#define ATT_S_OFF 31744
#define ATT_V0_OFF 8704
#define ATT_V1_OFF 36352
#define ATT_SMEM 64000

__global__ __launch_bounds__(256) void attn_mfma_kernel(
    const bf16* __restrict__ qkb, const bf16* __restrict__ gv,
    const float* __restrict__ pos_mult, bf16* __restrict__ ao) {
  __shared__ char smem[ATT_SMEM];
  bf16* P = (bf16*)(smem + ATT_P_OFF);
  bf16* Qs = (bf16*)(smem + ATT_Q_OFF);
  bf16* Ks = (bf16*)(smem + ATT_K_OFF);
  float* Ss = (float*)(smem + ATT_S_OFF);

  int t = threadIdx.x;
  int lane = t & 63;
  int w = t >> 6;
  int batch = blockIdx.x >> 6;
  int q0 = (blockIdx.x & 63) * 32;
  size_t tb = (size_t)batch * S_LEN;
  int jbase = q0 - 96;
  float cmul = log1pf(expf(pos_mult[0]));
  const float rs = 0.14433756729740643f;
  const short8v z8 = (short8v){0, 0, 0, 0, 0, 0, 0, 0};

  {
    int r = t >> 3, c = t & 7;
    short8v v = z8;
    if (c < 6) v = *reinterpret_cast<const short8v*>(qkb + (tb + q0 + r) * 96 + c * 8);
    *reinterpret_cast<short8v*>(Qs + r * LDAP + c * 8) = v;
  }
  {
    int r = t >> 1, h = t & 1;
    int j = jbase + r;
    if (j >= 0) {
      const bf16* krow = qkb + (tb + j) * 96 + 48 + h * 24;
      *reinterpret_cast<short8v*>(Ks + r * LDAP + h * 24) = *reinterpret_cast<const short8v*>(krow);
      *reinterpret_cast<short8v*>(Ks + r * LDAP + h * 24 + 8) = *reinterpret_cast<const short8v*>(krow + 8);
      *reinterpret_cast<short8v*>(Ks + r * LDAP + h * 24 + 16) = *reinterpret_cast<const short8v*>(krow + 16);
    } else {
      *reinterpret_cast<short8v*>(Ks + r * LDAP + h * 24) = z8;
      *reinterpret_cast<short8v*>(Ks + r * LDAP + h * 24 + 8) = z8;
      *reinterpret_cast<short8v*>(Ks + r * LDAP + h * 24 + 16) = z8;
    }
    if (h == 1) {
      *reinterpret_cast<short8v*>(Ks + r * LDAP + 48) = z8;
      *reinterpret_cast<short8v*>(Ks + r * LDAP + 56) = z8;
    }
  }
  __syncthreads();

  int m = lane & 15, g = lane >> 4;

  {
    f32x4 sacc[2][2];
#pragma unroll
    for (int mi = 0; mi < 2; ++mi)
#pragma unroll
      for (int ni = 0; ni < 2; ++ni) sacc[mi][ni] = (f32x4){0.f, 0.f, 0.f, 0.f};
#pragma unroll
    for (int ks = 0; ks < 2; ++ks) {
      int ko = ks * 32 + g * 8;
      fragT aq[2], bk[2];
#pragma unroll
      for (int mi = 0; mi < 2; ++mi)
        aq[mi] = *reinterpret_cast<const fragT*>(Qs + (mi * 16 + m) * LDAP + ko);
#pragma unroll
      for (int ni = 0; ni < 2; ++ni)
        bk[ni] = *reinterpret_cast<const fragT*>(Ks + (w * 32 + ni * 16 + m) * LDAP + ko);
#pragma unroll
      for (int mi = 0; mi < 2; ++mi)
#pragma unroll
        for (int ni = 0; ni < 2; ++ni)
          sacc[mi][ni] = __builtin_amdgcn_mfma_f32_16x16x32_bf16(aq[mi], bk[ni], sacc[mi][ni], 0, 0, 0);
    }
#pragma unroll
    for (int mi = 0; mi < 2; ++mi)
#pragma unroll
      for (int ni = 0; ni < 2; ++ni)
#pragma unroll
        for (int r = 0; r < 4; ++r) {
          int q = mi * 16 + g * 4 + r;
          int key = w * 32 + ni * 16 + m;
          int gi = q0 + q, gj = jbase + key;
          float s = (gj >= 0 && gj <= gi)
                        ? sacc[mi][ni][r] * rs + cmul * (float)(gj - gi)
                        : -INFINITY;
          Ss[q * 132 + key] = s;
        }
  }
  __syncthreads();

  auto stageV = [&](int c, unsigned bufoff) {
    int j = t >> 3;
    int c8 = t & 7;
    int gj = jbase + c * 32 + j;
    bf16* vb = (bf16*)(smem + bufoff);
    const bf16* vrow = gv + (tb + gj) * (size_t)DIM;
#pragma unroll
    for (int it = 0; it < 6; ++it) {
      int dj = c8 + it * 8;
      int d = dj * 8;
      short8v v = z8;
      if (gj >= 0) v = *reinterpret_cast<const short8v*>(vrow + d);
      *reinterpret_cast<short8v*>(vb + ((j >> 2) * 24 + (d >> 4)) * LDAP + (j & 3) * 16 + (d & 15)) = v;
    }
  };

  {
    int sq = t >> 3, sl = t & 7;
    union { float4 f4[4]; float f[16]; } su;
#pragma unroll
    for (int u = 0; u < 4; ++u)
      su.f4[u] = *reinterpret_cast<const float4*>(Ss + sq * 132 + sl * 16 + u * 4);
    __syncthreads();
    float mx = -INFINITY;
#pragma unroll
    for (int e = 0; e < 16; ++e) mx = fmaxf(mx, su.f[e]);
    mx = fmaxf(mx, __shfl_xor(mx, 1));
    mx = fmaxf(mx, __shfl_xor(mx, 2));
    mx = fmaxf(mx, __shfl_xor(mx, 4));
    float pv[16];
    float sum = 0.f;
#pragma unroll
    for (int e = 0; e < 16; ++e) {
      pv[e] = expf(su.f[e] - mx);
      sum += pv[e];
    }
    sum += __shfl_xor(sum, 1);
    sum += __shfl_xor(sum, 2);
    sum += __shfl_xor(sum, 4);
    float inv = 1.f / sum;
    union { bf16 b[16]; short8v s[2]; } pk;
#pragma unroll
    for (int e = 0; e < 16; ++e) pk.b[e] = __float2bfloat16(pv[e] * inv);
    bf16* pr = P + sq * 136 + sl * 16;
    *reinterpret_cast<short8v*>(pr) = pk.s[0];
    *reinterpret_cast<short8v*>(pr + 8) = pk.s[1];
  }
  stageV(0, ATT_V0_OFF);
  __syncthreads();

  f32x4 oacc[2][6];
#pragma unroll
  for (int mi = 0; mi < 2; ++mi)
#pragma unroll
    for (int nt = 0; nt < 6; ++nt) oacc[mi][nt] = (f32x4){0.f, 0.f, 0.f, 0.f};

  unsigned sbase = (unsigned)(size_t)(&smem[0]);
  unsigned lanebase = (unsigned)(((48 * g + 6 * w) * LDAP + m) * 2);

  for (int c = 0; c < 4; ++c) {
    unsigned vaddr = sbase + ((c & 1) ? ATT_V1_OFF : ATT_V0_OFF) + lanebase;
    fragT pa0 = *reinterpret_cast<const fragT*>(P + m * 136 + c * 32 + g * 8);
    fragT pa1 = *reinterpret_cast<const fragT*>(P + (16 + m) * 136 + c * 32 + g * 8);
    uint2v trr[12];
#pragma unroll
    for (int nt = 0; nt < 6; ++nt) {
      asm volatile("ds_read_b64_tr_b16 %0, %1" : "=v"(trr[2 * nt]) : "v"(vaddr + nt * 144));
      asm volatile("ds_read_b64_tr_b16 %0, %1" : "=v"(trr[2 * nt + 1]) : "v"(vaddr + nt * 144 + 3456));
    }
    asm volatile("s_waitcnt lgkmcnt(0)" ::: "memory");
    __builtin_amdgcn_sched_barrier(0);
    if (c < 3) stageV(c + 1, (c & 1) ? ATT_V0_OFF : ATT_V1_OFF);
#pragma unroll
    for (int nt = 0; nt < 6; ++nt) {
      union { int4v i4; fragT f; } u;
      u.i4 = (int4v){(int)trr[2 * nt].x, (int)trr[2 * nt].y,
                     (int)trr[2 * nt + 1].x, (int)trr[2 * nt + 1].y};
      oacc[0][nt] = __builtin_amdgcn_mfma_f32_16x16x32_bf16(pa0, u.f, oacc[0][nt], 0, 0, 0);
      oacc[1][nt] = __builtin_amdgcn_mfma_f32_16x16x32_bf16(pa1, u.f, oacc[1][nt], 0, 0, 0);
    }
    __syncthreads();
  }

#pragma unroll
  for (int mi = 0; mi < 2; ++mi)
#pragma unroll
    for (int nt = 0; nt < 6; ++nt) {
#pragma unroll
      for (int r = 0; r < 4; ++r) {
        int q = mi * 16 + g * 4 + r;
        int d = w * 96 + nt * 16 + m;
        ao[(tb + q0 + q) * (size_t)DIM + d] = __float2bfloat16(oacc[mi][nt][r]);
      }
    }
}

// ---------------- project GEMM (MFMA) + residual ----------------
__global__ __launch_bounds__(256) void project_mfma_kernel(
    const bf16* __restrict__ gl, const bf16* __restrict__ at,
    const bf16* __restrict__ wpb, const float* __restrict__ x,
    float* __restrict__ out) {
  __shared__ short As[128 * LDAP];
  __shared__ short Bs[128 * LDAP];
  int t = threadIdx.x;
  int row0 = blockIdx.x * 128;
  int col0 = blockIdx.y * 128;
  int lane = t & 63;
  int w = t >> 6;
  int wr = w >> 1, wc = w & 1;

  f32x4 acc[4][4];
#pragma unroll
  for (int i = 0; i < 4; ++i)
#pragma unroll
    for (int j = 0; j < 4; ++j) acc[i][j] = (f32x4){0.f, 0.f, 0.f, 0.f};

  int nrow[4];
  int kcol = (t & 7) * 8;
#pragma unroll
  for (int i = 0; i < 4; ++i) nrow[i] = (i * 256 + t) >> 3;

  auto loadA = [&](int kt, short8v* dst) {
    const bf16* ab = (kt < 6) ? gl : at;
    int kk0 = (kt < 6 ? kt : kt - 6) * 64 + kcol;
#pragma unroll
    for (int i = 0; i < 4; ++i)
      dst[i] = *reinterpret_cast<const short8v*>(ab + (size_t)(row0 + nrow[i]) * DIM + kk0);
  };
  auto loadB = [&](int kt, short8v* dst) {
    int kk0 = kt * 64 + kcol;
#pragma unroll
    for (int i = 0; i < 4; ++i)
      dst[i] = *reinterpret_cast<const short8v*>(wpb + (size_t)(col0 + nrow[i]) * 768 + kk0);
  };

  short8v ar[4], br[4];
  loadA(0, ar);
  loadB(0, br);

  for (int kt = 0; kt < 12; ++kt) {
    __syncthreads();
#pragma unroll
    for (int i = 0; i < 4; ++i) {
      *reinterpret_cast<short8v*>(&As[nrow[i] * LDAP + kcol]) = ar[i];
      *reinterpret_cast<short8v*>(&Bs[nrow[i] * LDAP + kcol]) = br[i];
    }
    __syncthreads();
    short8v an[4], bn[4];
    if (kt < 11) {
      loadA(kt + 1, an);
      loadB(kt + 1, bn);
    }
#pragma unroll
    for (int ks = 0; ks < 2; ++ks) {
      fragT af[4], bfv[4];
      int ko = ks * 32 + (lane >> 4) * 8;
#pragma unroll
      for (int mi = 0; mi < 4; ++mi)
        af[mi] = *reinterpret_cast<const fragT*>(&As[(wr * 64 + mi * 16 + (lane & 15)) * LDAP + ko]);
#pragma unroll
      for (int ni = 0; ni < 4; ++ni)
        bfv[ni] = *reinterpret_cast<const fragT*>(&Bs[(wc * 64 + ni * 16 + (lane & 15)) * LDAP + ko]);
#pragma unroll
      for (int mi = 0; mi < 4; ++mi)
#pragma unroll
        for (int ni = 0; ni < 4; ++ni)
          acc[mi][ni] = __builtin_amdgcn_mfma_f32_16x16x32_bf16(af[mi], bfv[ni], acc[mi][ni], 0, 0, 0);
    }
#pragma unroll
    for (int i = 0; i < 4; ++i) { ar[i] = an[i]; br[i] = bn[i]; }
  }

  int cl = lane & 15, rg = lane >> 4;
#pragma unroll
  for (int mi = 0; mi < 4; ++mi)
#pragma unroll
    for (int ni = 0; ni < 4; ++ni) {
      int d = col0 + wc * 64 + ni * 16 + cl;
#pragma unroll
      for (int r = 0; r < 4; ++r) {
        int token = row0 + wr * 64 + mi * 16 + rg * 4 + r;
        out[(size_t)token * DIM + d] = x[(size_t)token * DIM + d] + acc[mi][ni][r];
      }
    }
}

extern "C" void kernel_launch(void* const* d_in, const int* in_sizes, int n_in,
                              void* d_out, int out_size, void* d_ws, size_t ws_size,
                              hipStream_t stream) {
  (void)in_sizes; (void)n_in; (void)out_size; (void)ws_size;
  const float* x = (const float*)d_in[0];
  const float* nw = (const float*)d_in[1];
  const float* we = (const float*)d_in[2];
  const float* wp = (const float*)d_in[3];
  const float* pm = (const float*)d_in[4];
  char* ws = (char*)d_ws;
  bf16* xn = (bf16*)(ws);
  bf16* qk = (bf16*)(ws + 50331648);
  bf16* gl = (bf16*)(ws + 62914560);
  bf16* gv = (bf16*)(ws + 113246208);
  bf16* at = (bf16*)(ws + 163577856);
  bf16* web = (bf16*)(ws + 163577856);  // alias: consumed before `at` is written
  bf16* wpb = (bf16*)(ws + 213909504);
  float* out = (float*)d_out;

  hipLaunchKernelGGL(conv_kernel, dim3(512), dim3(256), 0, stream, we, wp, web, wpb);
  hipLaunchKernelGGL(ln_kernel, dim3(NTOK / 4), dim3(256), 0, stream, x, nw, xn);
  hipLaunchKernelGGL(expand_persist_kernel, dim3(NTOK / 128), dim3(256), 0, stream, xn, web, qk, gl, gv);
  hipLaunchKernelGGL(attn_mfma_kernel, dim3(NBATCH * (S_LEN / 32)), dim3(256), 0, stream, qk, gv, pm, at);
  hipLaunchKernelGGL(project_mfma_kernel, dim3(NTOK / 128, 3), dim3(256), 0, stream, gl, at, wpb, x, out);
}

// Round 5
// 287.551 us; speedup vs baseline: 1.3613x; 1.3613x over previous
//
#include <hip/hip_runtime.h>
#include <hip/hip_bf16.h>
#include <math.h>

#define S_LEN 2048
#define NBATCH 32
#define DIM 384
#define NTOK (NBATCH * S_LEN)

typedef __hip_bfloat16 bf16;
typedef __attribute__((ext_vector_type(8))) short short8v;
typedef __attribute__((ext_vector_type(4))) float f32x4;
typedef __attribute__((ext_vector_type(2))) unsigned int uint2v;
typedef __attribute__((ext_vector_type(4))) int int4v;
typedef short8v fragT;

#define LDAP 72  // padded LDS leading dim (halfwords)

__device__ __forceinline__ float bf2f(unsigned short u) {
  union { unsigned int i; float f; } c; c.i = ((unsigned int)u) << 16; return c.f;
}

// ---------------- weight fp32 -> bf16 conversion ----------------
__global__ __launch_bounds__(256) void conv_kernel(const float* __restrict__ we,
                                                   const float* __restrict__ wp,
                                                   bf16* __restrict__ web,
                                                   bf16* __restrict__ wpb) {
  int i = blockIdx.x * 256 + threadIdx.x;
  int stride = gridDim.x * 256;
  for (int j = i; j < 1632 * 384; j += stride) web[j] = __float2bfloat16(we[j]);
  for (int j = i; j < 384 * 768; j += stride) wpb[j] = __float2bfloat16(wp[j]);
}

// ---------------- LayerNorm: x (fp32) -> xn (bf16) ----------------
__global__ __launch_bounds__(256) void ln_kernel(const float* __restrict__ x,
                                                 const float* __restrict__ nw,
                                                 bf16* __restrict__ xn) {
  int token = blockIdx.x * 4 + (threadIdx.x >> 6);
  int lane = threadIdx.x & 63;
  const float* xr = x + (size_t)token * DIM;
  float v[6];
  float s = 0.f, sq = 0.f;
#pragma unroll
  for (int j = 0; j < 6; ++j) {
    v[j] = xr[lane + j * 64];
    s += v[j];
    sq += v[j] * v[j];
  }
#pragma unroll
  for (int o = 32; o; o >>= 1) {
    s += __shfl_xor(s, o);
    sq += __shfl_xor(sq, o);
  }
  float mu = s * (1.f / DIM);
  float var = sq * (1.f / DIM) - mu * mu;
  float rs = rsqrtf(var + 1e-5f);
  bf16* xo = xn + (size_t)token * DIM;
#pragma unroll
  for (int j = 0; j < 6; ++j) {
    int c = lane + j * 64;
    xo[c] = __float2bfloat16((v[j] - mu) * rs * nw[c]);
  }
}

// ---------------- wide expand GEMM (MFMA) + GEGLU epilogue ----------------
// BM=128 tokens x BN=256 h-cols, 4 waves (2M x 2N), 64 MFMA per wave per
// K-step. Flat grid 3584 = 512 x-tiles * 7 y-tiles, XCD-swizzled so each
// XCD runs all 7 y's of consecutive x-tiles back-to-back (A-tile L2-hot).
// y=0: qk cols 0..95 (wave 1 computes clamped garbage, writes nothing).
// y=1..6: 128 lin + 128 matching pre cols; wave-local lin/pre pairing.
__global__ __launch_bounds__(256, 2) void expand_wide_kernel(
    const bf16* __restrict__ xn, const bf16* __restrict__ web,
    bf16* __restrict__ qkb, bf16* __restrict__ gl, bf16* __restrict__ gv) {
  __shared__ short As[128 * LDAP];  // 18432 B
  __shared__ short Bs[256 * LDAP];  // 36864 B
  int t = threadIdx.x;
  int lane = t & 63, w = t >> 6;
  int wr = w >> 1, wc = w & 1;
  int m = lane & 15, g = lane >> 4;

  int bid = blockIdx.x;
  int logical = (bid & 7) * 448 + (bid >> 3);
  int xt = logical / 7, y = logical % 7;
  int row0 = xt * 128;

  // B global row for B-tile row r (0..255) of tile y
  auto brow_of = [&](int r) -> int {
    if (y == 0) return (r < 96) ? r : 95;  // clamp: harmless garbage
    int c0 = (y - 1) * 128;
    int half = r >> 7, nn = r & 127;
    return (nn < 64) ? (96 + c0 + half * 64 + nn)
                     : (864 + c0 + half * 64 + (nn - 64));
  };

  auto loadA = [&](int kt, short8v* arg) {
#pragma unroll
    for (int i = 0; i < 4; ++i) {
      int idx = i * 256 + t;
      int r = idx >> 3, c8 = idx & 7;
      arg[i] = *reinterpret_cast<const short8v*>(xn + (size_t)(row0 + r) * 384 + kt * 64 + c8 * 8);
    }
  };
  auto loadB = [&](int kt, short8v* brg) {
#pragma unroll
    for (int i = 0; i < 8; ++i) {
      int idx = i * 256 + t;
      int r = idx >> 3, c8 = idx & 7;
      brg[i] = *reinterpret_cast<const short8v*>(web + (size_t)brow_of(r) * 384 + kt * 64 + c8 * 8);
    }
  };

  f32x4 acc[4][8];
#pragma unroll
  for (int i = 0; i < 4; ++i)
#pragma unroll
    for (int j = 0; j < 8; ++j) acc[i][j] = (f32x4){0.f, 0.f, 0.f, 0.f};

  short8v arg[4], brg[8];
  loadA(0, arg);
  loadB(0, brg);

  for (int kt = 0; kt < 6; ++kt) {
    __syncthreads();
#pragma unroll
    for (int i = 0; i < 4; ++i) {
      int idx = i * 256 + t;
      int r = idx >> 3, c8 = idx & 7;
      *reinterpret_cast<short8v*>(&As[r * LDAP + c8 * 8]) = arg[i];
    }
#pragma unroll
    for (int i = 0; i < 8; ++i) {
      int idx = i * 256 + t;
      int r = idx >> 3, c8 = idx & 7;
      *reinterpret_cast<short8v*>(&Bs[r * LDAP + c8 * 8]) = brg[i];
    }
    __syncthreads();
    if (kt < 5) {
      loadA(kt + 1, arg);
      loadB(kt + 1, brg);
    }
#pragma unroll
    for (int ks = 0; ks < 2; ++ks) {
      int ko = ks * 32 + g * 8;
      fragT af[4], bfv[8];
#pragma unroll
      for (int mi = 0; mi < 4; ++mi)
        af[mi] = *reinterpret_cast<const fragT*>(&As[(wr * 64 + mi * 16 + m) * LDAP + ko]);
#pragma unroll
      for (int ni = 0; ni < 8; ++ni)
        bfv[ni] = *reinterpret_cast<const fragT*>(&Bs[(wc * 128 + ni * 16 + m) * LDAP + ko]);
#pragma unroll
      for (int mi = 0; mi < 4; ++mi)
#pragma unroll
        for (int ni = 0; ni < 8; ++ni)
          acc[mi][ni] = __builtin_amdgcn_mfma_f32_16x16x32_bf16(af[mi], bfv[ni], acc[mi][ni], 0, 0, 0);
    }
  }

  // ---- epilogue ----
  int cl = m, rg = g;
  if (y == 0) {
    if (wc == 0) {
#pragma unroll
      for (int mi = 0; mi < 4; ++mi)
#pragma unroll
        for (int ni = 0; ni < 6; ++ni) {
          int n = ni * 16 + cl;
          if (n < 96) {
#pragma unroll
            for (int r = 0; r < 4; ++r) {
              int token = row0 + wr * 64 + mi * 16 + rg * 4 + r;
              qkb[(size_t)token * 96 + n] = __float2bfloat16(acc[mi][ni][r]);
            }
          }
        }
    }
  } else {
    int c0 = (y - 1) * 128;
#pragma unroll
    for (int mi = 0; mi < 4; ++mi)
#pragma unroll
      for (int ni = 0; ni < 4; ++ni) {
        int c = c0 + wc * 64 + ni * 16 + cl;  // geglu col 0..767
#pragma unroll
        for (int r = 0; r < 4; ++r) {
          int token = row0 + wr * 64 + mi * 16 + rg * 4 + r;
          float lin = acc[mi][ni][r];
          float pre = acc[mi][ni + 4][r];
          float z = 0.79788456f * (pre + 0.044715f * pre * pre * pre);
          float gelu = pre * (1.f / (1.f + __expf(-2.f * z)));
          float gval = lin * gelu;
          if (c < 384)
            gl[(size_t)token * DIM + c] = __float2bfloat16(gval);
          else
            gv[(size_t)token * DIM + (c - 384)] = __float2bfloat16(gval);
        }
      }
  }
}

// ---------------- MFMA windowed causal attention ----------------
#define ATT_P_OFF 0
#define ATT_Q_OFF 8704
#define ATT_K_OFF 13312
#define ATT_S_OFF 31744
#define ATT_V0_OFF 8704
#define ATT_V1_OFF 36352
#define ATT_SMEM 64000

__global__ __launch_bounds__(256) void attn_mfma_kernel(
    const bf16* __restrict__ qkb, const bf16* __restrict__ gv,
    const float* __restrict__ pos_mult, bf16* __restrict__ ao) {
  __shared__ char smem[ATT_SMEM];
  bf16* P = (bf16*)(smem + ATT_P_OFF);
  bf16* Qs = (bf16*)(smem + ATT_Q_OFF);
  bf16* Ks = (bf16*)(smem + ATT_K_OFF);
  float* Ss = (float*)(smem + ATT_S_OFF);

  int t = threadIdx.x;
  int lane = t & 63;
  int w = t >> 6;
  int batch = blockIdx.x >> 6;
  int q0 = (blockIdx.x & 63) * 32;
  size_t tb = (size_t)batch * S_LEN;
  int jbase = q0 - 96;
  float cmul = log1pf(expf(pos_mult[0]));
  const float rs = 0.14433756729740643f;
  const short8v z8 = (short8v){0, 0, 0, 0, 0, 0, 0, 0};

  {
    int r = t >> 3, c = t & 7;
    short8v v = z8;
    if (c < 6) v = *reinterpret_cast<const short8v*>(qkb + (tb + q0 + r) * 96 + c * 8);
    *reinterpret_cast<short8v*>(Qs + r * LDAP + c * 8) = v;
  }
  {
    int r = t >> 1, h = t & 1;
    int j = jbase + r;
    if (j >= 0) {
      const bf16* krow = qkb + (tb + j) * 96 + 48 + h * 24;
      *reinterpret_cast<short8v*>(Ks + r * LDAP + h * 24) = *reinterpret_cast<const short8v*>(krow);
      *reinterpret_cast<short8v*>(Ks + r * LDAP + h * 24 + 8) = *reinterpret_cast<const short8v*>(krow + 8);
      *reinterpret_cast<short8v*>(Ks + r * LDAP + h * 24 + 16) = *reinterpret_cast<const short8v*>(krow + 16);
    } else {
      *reinterpret_cast<short8v*>(Ks + r * LDAP + h * 24) = z8;
      *reinterpret_cast<short8v*>(Ks + r * LDAP + h * 24 + 8) = z8;
      *reinterpret_cast<short8v*>(Ks + r * LDAP + h * 24 + 16) = z8;
    }
    if (h == 1) {
      *reinterpret_cast<short8v*>(Ks + r * LDAP + 48) = z8;
      *reinterpret_cast<short8v*>(Ks + r * LDAP + 56) = z8;
    }
  }
  __syncthreads();

  int m = lane & 15, g = lane >> 4;

  {
    f32x4 sacc[2][2];
#pragma unroll
    for (int mi = 0; mi < 2; ++mi)
#pragma unroll
      for (int ni = 0; ni < 2; ++ni) sacc[mi][ni] = (f32x4){0.f, 0.f, 0.f, 0.f};
#pragma unroll
    for (int ks = 0; ks < 2; ++ks) {
      int ko = ks * 32 + g * 8;
      fragT aq[2], bk[2];
#pragma unroll
      for (int mi = 0; mi < 2; ++mi)
        aq[mi] = *reinterpret_cast<const fragT*>(Qs + (mi * 16 + m) * LDAP + ko);
#pragma unroll
      for (int ni = 0; ni < 2; ++ni)
        bk[ni] = *reinterpret_cast<const fragT*>(Ks + (w * 32 + ni * 16 + m) * LDAP + ko);
#pragma unroll
      for (int mi = 0; mi < 2; ++mi)
#pragma unroll
        for (int ni = 0; ni < 2; ++ni)
          sacc[mi][ni] = __builtin_amdgcn_mfma_f32_16x16x32_bf16(aq[mi], bk[ni], sacc[mi][ni], 0, 0, 0);
    }
#pragma unroll
    for (int mi = 0; mi < 2; ++mi)
#pragma unroll
      for (int ni = 0; ni < 2; ++ni)
#pragma unroll
        for (int r = 0; r < 4; ++r) {
          int q = mi * 16 + g * 4 + r;
          int key = w * 32 + ni * 16 + m;
          int gi = q0 + q, gj = jbase + key;
          float s = (gj >= 0 && gj <= gi)
                        ? sacc[mi][ni][r] * rs + cmul * (float)(gj - gi)
                        : -INFINITY;
          Ss[q * 132 + key] = s;
        }
  }
  __syncthreads();

  auto stageV = [&](int c, unsigned bufoff) {
    int j = t >> 3;
    int c8 = t & 7;
    int gj = jbase + c * 32 + j;
    bf16* vb = (bf16*)(smem + bufoff);
    const bf16* vrow = gv + (tb + gj) * (size_t)DIM;
#pragma unroll
    for (int it = 0; it < 6; ++it) {
      int dj = c8 + it * 8;
      int d = dj * 8;
      short8v v = z8;
      if (gj >= 0) v = *reinterpret_cast<const short8v*>(vrow + d);
      *reinterpret_cast<short8v*>(vb + ((j >> 2) * 24 + (d >> 4)) * LDAP + (j & 3) * 16 + (d & 15)) = v;
    }
  };

  {
    int sq = t >> 3, sl = t & 7;
    union { float4 f4[4]; float f[16]; } su;
#pragma unroll
    for (int u = 0; u < 4; ++u)
      su.f4[u] = *reinterpret_cast<const float4*>(Ss + sq * 132 + sl * 16 + u * 4);
    __syncthreads();
    float mx = -INFINITY;
#pragma unroll
    for (int e = 0; e < 16; ++e) mx = fmaxf(mx, su.f[e]);
    mx = fmaxf(mx, __shfl_xor(mx, 1));
    mx = fmaxf(mx, __shfl_xor(mx, 2));
    mx = fmaxf(mx, __shfl_xor(mx, 4));
    float pv[16];
    float sum = 0.f;
#pragma unroll
    for (int e = 0; e < 16; ++e) {
      pv[e] = expf(su.f[e] - mx);
      sum += pv[e];
    }
    sum += __shfl_xor(sum, 1);
    sum += __shfl_xor(sum, 2);
    sum += __shfl_xor(sum, 4);
    float inv = 1.f / sum;
    union { bf16 b[16]; short8v s[2]; } pk;
#pragma unroll
    for (int e = 0; e < 16; ++e) pk.b[e] = __float2bfloat16(pv[e] * inv);
    bf16* pr = P + sq * 136 + sl * 16;
    *reinterpret_cast<short8v*>(pr) = pk.s[0];
    *reinterpret_cast<short8v*>(pr + 8) = pk.s[1];
  }
  stageV(0, ATT_V0_OFF);
  __syncthreads();

  f32x4 oacc[2][6];
#pragma unroll
  for (int mi = 0; mi < 2; ++mi)
#pragma unroll
    for (int nt = 0; nt < 6; ++nt) oacc[mi][nt] = (f32x4){0.f, 0.f, 0.f, 0.f};

  unsigned sbase = (unsigned)(size_t)(&smem[0]);
  unsigned lanebase = (unsigned)(((48 * g + 6 * w) * LDAP + m) * 2);

  for (int c = 0; c < 4; ++c) {
    unsigned vaddr = sbase + ((c & 1) ? ATT_V1_OFF : ATT_V0_OFF) + lanebase;
    fragT pa0 = *reinterpret_cast<const fragT*>(P + m * 136 + c * 32 + g * 8);
    fragT pa1 = *reinterpret_cast<const fragT*>(P + (16 + m) * 136 + c * 32 + g * 8);
    uint2v trr[12];
#pragma unroll
    for (int nt = 0; nt < 6; ++nt) {
      asm volatile("ds_read_b64_tr_b16 %0, %1" : "=v"(trr[2 * nt]) : "v"(vaddr + nt * 144));
      asm volatile("ds_read_b64_tr_b16 %0, %1" : "=v"(trr[2 * nt + 1]) : "v"(vaddr + nt * 144 + 3456));
    }
    asm volatile("s_waitcnt lgkmcnt(0)" ::: "memory");
    __builtin_amdgcn_sched_barrier(0);
    if (c < 3) stageV(c + 1, (c & 1) ? ATT_V0_OFF : ATT_V1_OFF);
#pragma unroll
    for (int nt = 0; nt < 6; ++nt) {
      union { int4v i4; fragT f; } u;
      u.i4 = (int4v){(int)trr[2 * nt].x, (int)trr[2 * nt].y,
                     (int)trr[2 * nt + 1].x, (int)trr[2 * nt + 1].y};
      oacc[0][nt] = __builtin_amdgcn_mfma_f32_16x16x32_bf16(pa0, u.f, oacc[0][nt], 0, 0, 0);
      oacc[1][nt] = __builtin_amdgcn_mfma_f32_16x16x32_bf16(pa1, u.f, oacc[1][nt], 0, 0, 0);
    }
    __syncthreads();
  }

#pragma unroll
  for (int mi = 0; mi < 2; ++mi)
#pragma unroll
    for (int nt = 0; nt < 6; ++nt) {
#pragma unroll
      for (int r = 0; r < 4; ++r) {
        int q = mi * 16 + g * 4 + r;
        int d = w * 96 + nt * 16 + m;
        ao[(tb + q0 + q) * (size_t)DIM + d] = __float2bfloat16(oacc[mi][nt][r]);
      }
    }
}

// ---------------- project GEMM (MFMA) + residual ----------------
// Flat grid 1536 = 512 x-tiles * 3 col-tiles, XCD-swizzled (col-inner).
__global__ __launch_bounds__(256) void project_mfma_kernel(
    const bf16* __restrict__ gl, const bf16* __restrict__ at,
    const bf16* __restrict__ wpb, const float* __restrict__ x,
    float* __restrict__ out) {
  __shared__ short As[128 * LDAP];
  __shared__ short Bs[128 * LDAP];
  int t = threadIdx.x;
  int bid = blockIdx.x;
  int logical = (bid & 7) * 192 + (bid >> 3);
  int row0 = (logical / 3) * 128;
  int col0 = (logical % 3) * 128;
  int lane = t & 63;
  int w = t >> 6;
  int wr = w >> 1, wc = w & 1;

  f32x4 acc[4][4];
#pragma unroll
  for (int i = 0; i < 4; ++i)
#pragma unroll
    for (int j = 0; j < 4; ++j) acc[i][j] = (f32x4){0.f, 0.f, 0.f, 0.f};

  int nrow[4];
  int kcol = (t & 7) * 8;
#pragma unroll
  for (int i = 0; i < 4; ++i) nrow[i] = (i * 256 + t) >> 3;

  auto loadA = [&](int kt, short8v* dst) {
    const bf16* ab = (kt < 6) ? gl : at;
    int kk0 = (kt < 6 ? kt : kt - 6) * 64 + kcol;
#pragma unroll
    for (int i = 0; i < 4; ++i)
      dst[i] = *reinterpret_cast<const short8v*>(ab + (size_t)(row0 + nrow[i]) * DIM + kk0);
  };
  auto loadB = [&](int kt, short8v* dst) {
    int kk0 = kt * 64 + kcol;
#pragma unroll
    for (int i = 0; i < 4; ++i)
      dst[i] = *reinterpret_cast<const short8v*>(wpb + (size_t)(col0 + nrow[i]) * 768 + kk0);
  };

  short8v ar[4], br[4];
  loadA(0, ar);
  loadB(0, br);

  for (int kt = 0; kt < 12; ++kt) {
    __syncthreads();
#pragma unroll
    for (int i = 0; i < 4; ++i) {
      *reinterpret_cast<short8v*>(&As[nrow[i] * LDAP + kcol]) = ar[i];
      *reinterpret_cast<short8v*>(&Bs[nrow[i] * LDAP + kcol]) = br[i];
    }
    __syncthreads();
    short8v an[4], bn[4];
    if (kt < 11) {
      loadA(kt + 1, an);
      loadB(kt + 1, bn);
    }
#pragma unroll
    for (int ks = 0; ks < 2; ++ks) {
      fragT af[4], bfv[4];
      int ko = ks * 32 + (lane >> 4) * 8;
#pragma unroll
      for (int mi = 0; mi < 4; ++mi)
        af[mi] = *reinterpret_cast<const fragT*>(&As[(wr * 64 + mi * 16 + (lane & 15)) * LDAP + ko]);
#pragma unroll
      for (int ni = 0; ni < 4; ++ni)
        bfv[ni] = *reinterpret_cast<const fragT*>(&Bs[(wc * 64 + ni * 16 + (lane & 15)) * LDAP + ko]);
#pragma unroll
      for (int mi = 0; mi < 4; ++mi)
#pragma unroll
        for (int ni = 0; ni < 4; ++ni)
          acc[mi][ni] = __builtin_amdgcn_mfma_f32_16x16x32_bf16(af[mi], bfv[ni], acc[mi][ni], 0, 0, 0);
    }
#pragma unroll
    for (int i = 0; i < 4; ++i) { ar[i] = an[i]; br[i] = bn[i]; }
  }

  int cl = lane & 15, rg = lane >> 4;
#pragma unroll
  for (int mi = 0; mi < 4; ++mi)
#pragma unroll
    for (int ni = 0; ni < 4; ++ni) {
      int d = col0 + wc * 64 + ni * 16 + cl;
#pragma unroll
      for (int r = 0; r < 4; ++r) {
        int token = row0 + wr * 64 + mi * 16 + rg * 4 + r;
        out[(size_t)token * DIM + d] = x[(size_t)token * DIM + d] + acc[mi][ni][r];
      }
    }
}

extern "C" void kernel_launch(void* const* d_in, const int* in_sizes, int n_in,
                              void* d_out, int out_size, void* d_ws, size_t ws_size,
                              hipStream_t stream) {
  (void)in_sizes; (void)n_in; (void)out_size; (void)ws_size;
  const float* x = (const float*)d_in[0];
  const float* nw = (const float*)d_in[1];
  const float* we = (const float*)d_in[2];
  const float* wp = (const float*)d_in[3];
  const float* pm = (const float*)d_in[4];
  char* ws = (char*)d_ws;
  bf16* xn = (bf16*)(ws);
  bf16* qk = (bf16*)(ws + 50331648);
  bf16* gl = (bf16*)(ws + 62914560);
  bf16* gv = (bf16*)(ws + 113246208);
  bf16* at = (bf16*)(ws + 163577856);
  bf16* web = (bf16*)(ws + 163577856);  // alias: consumed before `at` is written
  bf16* wpb = (bf16*)(ws + 213909504);
  float* out = (float*)d_out;

  hipLaunchKernelGGL(conv_kernel, dim3(512), dim3(256), 0, stream, we, wp, web, wpb);
  hipLaunchKernelGGL(ln_kernel, dim3(NTOK / 4), dim3(256), 0, stream, x, nw, xn);
  hipLaunchKernelGGL(expand_wide_kernel, dim3(512 * 7), dim3(256), 0, stream, xn, web, qk, gl, gv);
  hipLaunchKernelGGL(attn_mfma_kernel, dim3(NBATCH * (S_LEN / 32)), dim3(256), 0, stream, qk, gv, pm, at);
  hipLaunchKernelGGL(project_mfma_kernel, dim3(512 * 3), dim3(256), 0, stream, gl, at, wpb, x, out);
}

// Round 6
// 279.847 us; speedup vs baseline: 1.3988x; 1.0275x over previous
//
#include <hip/hip_runtime.h>
#include <hip/hip_bf16.h>
#include <math.h>

#define S_LEN 2048
#define NBATCH 32
#define DIM 384
#define NTOK (NBATCH * S_LEN)

typedef __hip_bfloat16 bf16;
typedef __attribute__((ext_vector_type(8))) short short8v;
typedef __attribute__((ext_vector_type(4))) float f32x4;
typedef __attribute__((ext_vector_type(2))) unsigned int uint2v;
typedef __attribute__((ext_vector_type(4))) int int4v;
typedef short8v fragT;

#define LDAP 72  // padded LDS leading dim (halfwords) for 64-wide K chunks

__device__ __forceinline__ float bf2f(unsigned short u) {
  union { unsigned int i; float f; } c; c.i = ((unsigned int)u) << 16; return c.f;
}

// ---------------- weight fp32 -> bf16 conversion ----------------
__global__ __launch_bounds__(256) void conv_kernel(const float* __restrict__ we,
                                                   const float* __restrict__ wp,
                                                   bf16* __restrict__ web,
                                                   bf16* __restrict__ wpb) {
  int i = blockIdx.x * 256 + threadIdx.x;
  int stride = gridDim.x * 256;
  for (int j = i; j < 1632 * 384; j += stride) web[j] = __float2bfloat16(we[j]);
  for (int j = i; j < 384 * 768; j += stride) wpb[j] = __float2bfloat16(wp[j]);
}

// ---------------- LayerNorm: x (fp32) -> xn (bf16) ----------------
__global__ __launch_bounds__(256) void ln_kernel(const float* __restrict__ x,
                                                 const float* __restrict__ nw,
                                                 bf16* __restrict__ xn) {
  int token = blockIdx.x * 4 + (threadIdx.x >> 6);
  int lane = threadIdx.x & 63;
  const float* xr = x + (size_t)token * DIM;
  float v[6];
  float s = 0.f, sq = 0.f;
#pragma unroll
  for (int j = 0; j < 6; ++j) {
    v[j] = xr[lane + j * 64];
    s += v[j];
    sq += v[j] * v[j];
  }
#pragma unroll
  for (int o = 32; o; o >>= 1) {
    s += __shfl_xor(s, o);
    sq += __shfl_xor(sq, o);
  }
  float mu = s * (1.f / DIM);
  float var = sq * (1.f / DIM) - mu * mu;
  float rs = rsqrtf(var + 1e-5f);
  bf16* xo = xn + (size_t)token * DIM;
#pragma unroll
  for (int j = 0; j < 6; ++j) {
    int c = lane + j * 64;
    xo[c] = __float2bfloat16((v[j] - mu) * rs * nw[c]);
  }
}

// ---------------- expand GEMM: dbuf single-barrier pipeline ----------------
// BM=128 x BN=256, BK=32, 12 K-steps, 4 waves (2M x 2N). Double-buffered LDS,
// ONE barrier per step; reg-staging 2 steps deep. XCD-swizzled flat grid
// 3584 = 512 x-tiles * 7 y-tiles (y=0: qk; y=1..6: 128 lin + 128 pre cols).
#define EBP 40  // 32 + 8 pad (halfwords)
__global__ __launch_bounds__(256, 2) void expand_db_kernel(
    const bf16* __restrict__ xn, const bf16* __restrict__ web,
    bf16* __restrict__ qkb, bf16* __restrict__ gl, bf16* __restrict__ gv) {
  __shared__ short Abuf[2][128 * EBP];  // 20480 B
  __shared__ short Bbuf[2][256 * EBP];  // 40960 B
  int t = threadIdx.x;
  int lane = t & 63, w = t >> 6;
  int wr = w >> 1, wc = w & 1;
  int m = lane & 15, g = lane >> 4;

  int bid = blockIdx.x;
  int logical = (bid & 7) * 448 + (bid >> 3);
  int xt = logical / 7, y = logical % 7;
  int row0 = xt * 128;

  int aR[2], aS[2], bR[4], bS[4], bRow[4];
#pragma unroll
  for (int i = 0; i < 2; ++i) { int idx = i * 256 + t; aR[i] = idx >> 2; aS[i] = idx & 3; }
#pragma unroll
  for (int i = 0; i < 4; ++i) {
    int idx = i * 256 + t;
    bR[i] = idx >> 2; bS[i] = idx & 3;
    int r = bR[i], brow;
    if (y == 0) brow = (r < 96) ? r : 95;  // clamp: harmless garbage
    else {
      int c0 = (y - 1) * 128, half = r >> 7, nn = r & 127;
      brow = (nn < 64) ? (96 + c0 + half * 64 + nn) : (864 + c0 + half * 64 + (nn - 64));
    }
    bRow[i] = brow;
  }

  auto loadA = [&](int kt, short8v* d) {
#pragma unroll
    for (int i = 0; i < 2; ++i)
      d[i] = *reinterpret_cast<const short8v*>(xn + (size_t)(row0 + aR[i]) * 384 + kt * 32 + aS[i] * 8);
  };
  auto loadB = [&](int kt, short8v* d) {
#pragma unroll
    for (int i = 0; i < 4; ++i)
      d[i] = *reinterpret_cast<const short8v*>(web + (size_t)bRow[i] * 384 + kt * 32 + bS[i] * 8);
  };
  auto writeAB = [&](int p, const short8v* a, const short8v* b) {
#pragma unroll
    for (int i = 0; i < 2; ++i)
      *reinterpret_cast<short8v*>(&Abuf[p][aR[i] * EBP + aS[i] * 8]) = a[i];
#pragma unroll
    for (int i = 0; i < 4; ++i)
      *reinterpret_cast<short8v*>(&Bbuf[p][bR[i] * EBP + bS[i] * 8]) = b[i];
  };

  f32x4 acc[4][8];
#pragma unroll
  for (int i = 0; i < 4; ++i)
#pragma unroll
    for (int j = 0; j < 8; ++j) acc[i][j] = (f32x4){0.f, 0.f, 0.f, 0.f};

  short8v a0[2], b0[4], a1[2], b1[4];
  loadA(0, a0); loadB(0, b0);   // data(0) -> set0
  loadA(1, a1); loadB(1, b1);   // data(1) -> set1
  writeAB(0, a0, b0);           // buf0 <- data(0)
  __syncthreads();

#pragma unroll
  for (int s = 0; s < 12; ++s) {
    int p = s & 1;
    if (s < 11) {               // buf[p^1] <- data(s+1), held in set[(s+1)&1]
      if (s & 1) writeAB(p ^ 1, a0, b0);
      else       writeAB(p ^ 1, a1, b1);
    }
    if (s < 10) {               // issue data(s+2) -> set[s&1] (dead after its write)
      if (s & 1) { loadA(s + 2, a1); loadB(s + 2, b1); }
      else       { loadA(s + 2, a0); loadB(s + 2, b0); }
    }
    fragT af[4], bf8[8];
#pragma unroll
    for (int mi = 0; mi < 4; ++mi)
      af[mi] = *reinterpret_cast<const fragT*>(&Abuf[p][(wr * 64 + mi * 16 + m) * EBP + g * 8]);
#pragma unroll
    for (int ni = 0; ni < 8; ++ni)
      bf8[ni] = *reinterpret_cast<const fragT*>(&Bbuf[p][(wc * 128 + ni * 16 + m) * EBP + g * 8]);
    __builtin_amdgcn_s_setprio(1);
#pragma unroll
    for (int mi = 0; mi < 4; ++mi)
#pragma unroll
      for (int ni = 0; ni < 8; ++ni)
        acc[mi][ni] = __builtin_amdgcn_mfma_f32_16x16x32_bf16(af[mi], bf8[ni], acc[mi][ni], 0, 0, 0);
    __builtin_amdgcn_s_setprio(0);
    __syncthreads();
  }

  // ---- epilogue ----
  int cl = m, rg = g;
  if (y == 0) {
    if (wc == 0) {
#pragma unroll
      for (int mi = 0; mi < 4; ++mi)
#pragma unroll
        for (int ni = 0; ni < 6; ++ni) {
          int n = ni * 16 + cl;
          if (n < 96) {
#pragma unroll
            for (int r = 0; r < 4; ++r) {
              int token = row0 + wr * 64 + mi * 16 + rg * 4 + r;
              qkb[(size_t)token * 96 + n] = __float2bfloat16(acc[mi][ni][r]);
            }
          }
        }
    }
  } else {
    int c0 = (y - 1) * 128;
#pragma unroll
    for (int mi = 0; mi < 4; ++mi)
#pragma unroll
      for (int ni = 0; ni < 4; ++ni) {
        int c = c0 + wc * 64 + ni * 16 + cl;
#pragma unroll
        for (int r = 0; r < 4; ++r) {
          int token = row0 + wr * 64 + mi * 16 + rg * 4 + r;
          float lin = acc[mi][ni][r];
          float pre = acc[mi][ni + 4][r];
          float z = 0.79788456f * (pre + 0.044715f * pre * pre * pre);
          float gelu = pre * (1.f / (1.f + __expf(-2.f * z)));
          float gval = lin * gelu;
          if (c < 384)
            gl[(size_t)token * DIM + c] = __float2bfloat16(gval);
          else
            gv[(size_t)token * DIM + (c - 384)] = __float2bfloat16(gval);
        }
      }
  }
}

// ---------------- MFMA windowed causal attention (unchanged) ----------------
#define ATT_P_OFF 0
#define ATT_Q_OFF 8704
#define ATT_K_OFF 13312
#define ATT_S_OFF 31744
#define ATT_V0_OFF 8704
#define ATT_V1_OFF 36352
#define ATT_SMEM 64000

__global__ __launch_bounds__(256) void attn_mfma_kernel(
    const bf16* __restrict__ qkb, const bf16* __restrict__ gv,
    const float* __restrict__ pos_mult, bf16* __restrict__ ao) {
  __shared__ char smem[ATT_SMEM];
  bf16* P = (bf16*)(smem + ATT_P_OFF);
  bf16* Qs = (bf16*)(smem + ATT_Q_OFF);
  bf16* Ks = (bf16*)(smem + ATT_K_OFF);
  float* Ss = (float*)(smem + ATT_S_OFF);

  int t = threadIdx.x;
  int lane = t & 63;
  int w = t >> 6;
  int batch = blockIdx.x >> 6;
  int q0 = (blockIdx.x & 63) * 32;
  size_t tb = (size_t)batch * S_LEN;
  int jbase = q0 - 96;
  float cmul = log1pf(expf(pos_mult[0]));
  const float rs = 0.14433756729740643f;
  const short8v z8 = (short8v){0, 0, 0, 0, 0, 0, 0, 0};

  {
    int r = t >> 3, c = t & 7;
    short8v v = z8;
    if (c < 6) v = *reinterpret_cast<const short8v*>(qkb + (tb + q0 + r) * 96 + c * 8);
    *reinterpret_cast<short8v*>(Qs + r * LDAP + c * 8) = v;
  }
  {
    int r = t >> 1, h = t & 1;
    int j = jbase + r;
    if (j >= 0) {
      const bf16* krow = qkb + (tb + j) * 96 + 48 + h * 24;
      *reinterpret_cast<short8v*>(Ks + r * LDAP + h * 24) = *reinterpret_cast<const short8v*>(krow);
      *reinterpret_cast<short8v*>(Ks + r * LDAP + h * 24 + 8) = *reinterpret_cast<const short8v*>(krow + 8);
      *reinterpret_cast<short8v*>(Ks + r * LDAP + h * 24 + 16) = *reinterpret_cast<const short8v*>(krow + 16);
    } else {
      *reinterpret_cast<short8v*>(Ks + r * LDAP + h * 24) = z8;
      *reinterpret_cast<short8v*>(Ks + r * LDAP + h * 24 + 8) = z8;
      *reinterpret_cast<short8v*>(Ks + r * LDAP + h * 24 + 16) = z8;
    }
    if (h == 1) {
      *reinterpret_cast<short8v*>(Ks + r * LDAP + 48) = z8;
      *reinterpret_cast<short8v*>(Ks + r * LDAP + 56) = z8;
    }
  }
  __syncthreads();

  int m = lane & 15, g = lane >> 4;

  {
    f32x4 sacc[2][2];
#pragma unroll
    for (int mi = 0; mi < 2; ++mi)
#pragma unroll
      for (int ni = 0; ni < 2; ++ni) sacc[mi][ni] = (f32x4){0.f, 0.f, 0.f, 0.f};
#pragma unroll
    for (int ks = 0; ks < 2; ++ks) {
      int ko = ks * 32 + g * 8;
      fragT aq[2], bk[2];
#pragma unroll
      for (int mi = 0; mi < 2; ++mi)
        aq[mi] = *reinterpret_cast<const fragT*>(Qs + (mi * 16 + m) * LDAP + ko);
#pragma unroll
      for (int ni = 0; ni < 2; ++ni)
        bk[ni] = *reinterpret_cast<const fragT*>(Ks + (w * 32 + ni * 16 + m) * LDAP + ko);
#pragma unroll
      for (int mi = 0; mi < 2; ++mi)
#pragma unroll
        for (int ni = 0; ni < 2; ++ni)
          sacc[mi][ni] = __builtin_amdgcn_mfma_f32_16x16x32_bf16(aq[mi], bk[ni], sacc[mi][ni], 0, 0, 0);
    }
#pragma unroll
    for (int mi = 0; mi < 2; ++mi)
#pragma unroll
      for (int ni = 0; ni < 2; ++ni)
#pragma unroll
        for (int r = 0; r < 4; ++r) {
          int q = mi * 16 + g * 4 + r;
          int key = w * 32 + ni * 16 + m;
          int gi = q0 + q, gj = jbase + key;
          float s = (gj >= 0 && gj <= gi)
                        ? sacc[mi][ni][r] * rs + cmul * (float)(gj - gi)
                        : -INFINITY;
          Ss[q * 132 + key] = s;
        }
  }
  __syncthreads();

  auto stageV = [&](int c, unsigned bufoff) {
    int j = t >> 3;
    int c8 = t & 7;
    int gj = jbase + c * 32 + j;
    bf16* vb = (bf16*)(smem + bufoff);
    const bf16* vrow = gv + (tb + gj) * (size_t)DIM;
#pragma unroll
    for (int it = 0; it < 6; ++it) {
      int dj = c8 + it * 8;
      int d = dj * 8;
      short8v v = z8;
      if (gj >= 0) v = *reinterpret_cast<const short8v*>(vrow + d);
      *reinterpret_cast<short8v*>(vb + ((j >> 2) * 24 + (d >> 4)) * LDAP + (j & 3) * 16 + (d & 15)) = v;
    }
  };

  {
    int sq = t >> 3, sl = t & 7;
    union { float4 f4[4]; float f[16]; } su;
#pragma unroll
    for (int u = 0; u < 4; ++u)
      su.f4[u] = *reinterpret_cast<const float4*>(Ss + sq * 132 + sl * 16 + u * 4);
    __syncthreads();
    float mx = -INFINITY;
#pragma unroll
    for (int e = 0; e < 16; ++e) mx = fmaxf(mx, su.f[e]);
    mx = fmaxf(mx, __shfl_xor(mx, 1));
    mx = fmaxf(mx, __shfl_xor(mx, 2));
    mx = fmaxf(mx, __shfl_xor(mx, 4));
    float pv[16];
    float sum = 0.f;
#pragma unroll
    for (int e = 0; e < 16; ++e) {
      pv[e] = expf(su.f[e] - mx);
      sum += pv[e];
    }
    sum += __shfl_xor(sum, 1);
    sum += __shfl_xor(sum, 2);
    sum += __shfl_xor(sum, 4);
    float inv = 1.f / sum;
    union { bf16 b[16]; short8v s[2]; } pk;
#pragma unroll
    for (int e = 0; e < 16; ++e) pk.b[e] = __float2bfloat16(pv[e] * inv);
    bf16* pr = P + sq * 136 + sl * 16;
    *reinterpret_cast<short8v*>(pr) = pk.s[0];
    *reinterpret_cast<short8v*>(pr + 8) = pk.s[1];
  }
  stageV(0, ATT_V0_OFF);
  __syncthreads();

  f32x4 oacc[2][6];
#pragma unroll
  for (int mi = 0; mi < 2; ++mi)
#pragma unroll
    for (int nt = 0; nt < 6; ++nt) oacc[mi][nt] = (f32x4){0.f, 0.f, 0.f, 0.f};

  unsigned sbase = (unsigned)(size_t)(&smem[0]);
  unsigned lanebase = (unsigned)(((48 * g + 6 * w) * LDAP + m) * 2);

  for (int c = 0; c < 4; ++c) {
    unsigned vaddr = sbase + ((c & 1) ? ATT_V1_OFF : ATT_V0_OFF) + lanebase;
    fragT pa0 = *reinterpret_cast<const fragT*>(P + m * 136 + c * 32 + g * 8);
    fragT pa1 = *reinterpret_cast<const fragT*>(P + (16 + m) * 136 + c * 32 + g * 8);
    uint2v trr[12];
#pragma unroll
    for (int nt = 0; nt < 6; ++nt) {
      asm volatile("ds_read_b64_tr_b16 %0, %1" : "=v"(trr[2 * nt]) : "v"(vaddr + nt * 144));
      asm volatile("ds_read_b64_tr_b16 %0, %1" : "=v"(trr[2 * nt + 1]) : "v"(vaddr + nt * 144 + 3456));
    }
    asm volatile("s_waitcnt lgkmcnt(0)" ::: "memory");
    __builtin_amdgcn_sched_barrier(0);
    if (c < 3) stageV(c + 1, (c & 1) ? ATT_V0_OFF : ATT_V1_OFF);
#pragma unroll
    for (int nt = 0; nt < 6; ++nt) {
      union { int4v i4; fragT f; } u;
      u.i4 = (int4v){(int)trr[2 * nt].x, (int)trr[2 * nt].y,
                     (int)trr[2 * nt + 1].x, (int)trr[2 * nt + 1].y};
      oacc[0][nt] = __builtin_amdgcn_mfma_f32_16x16x32_bf16(pa0, u.f, oacc[0][nt], 0, 0, 0);
      oacc[1][nt] = __builtin_amdgcn_mfma_f32_16x16x32_bf16(pa1, u.f, oacc[1][nt], 0, 0, 0);
    }
    __syncthreads();
  }

#pragma unroll
  for (int mi = 0; mi < 2; ++mi)
#pragma unroll
    for (int nt = 0; nt < 6; ++nt) {
#pragma unroll
      for (int r = 0; r < 4; ++r) {
        int q = mi * 16 + g * 4 + r;
        int d = w * 96 + nt * 16 + m;
        ao[(tb + q0 + q) * (size_t)DIM + d] = __float2bfloat16(oacc[mi][nt][r]);
      }
    }
}

// ---------------- project GEMM: dbuf single-barrier pipeline ----------------
// BM=128 x BN=128, K=768 ([gl | attn]), BK=64, 12 steps, dbuf, one barrier/step.
__global__ __launch_bounds__(256, 2) void project_db_kernel(
    const bf16* __restrict__ gl, const bf16* __restrict__ at,
    const bf16* __restrict__ wpb, const float* __restrict__ x,
    float* __restrict__ out) {
  __shared__ short Abuf[2][128 * LDAP];  // 36864 B
  __shared__ short Bbuf[2][128 * LDAP];  // 36864 B
  int t = threadIdx.x;
  int bid = blockIdx.x;
  int logical = (bid & 7) * 192 + (bid >> 3);
  int row0 = (logical / 3) * 128;
  int col0 = (logical % 3) * 128;
  int lane = t & 63, w = t >> 6;
  int wr = w >> 1, wc = w & 1;
  int m = lane & 15, g = lane >> 4;

  int rI[4], c8 = t & 7;
#pragma unroll
  for (int i = 0; i < 4; ++i) rI[i] = i * 32 + (t >> 3);

  auto loadA = [&](int kt, short8v* d) {
    const bf16* ab = (kt < 6) ? gl : at;
    int kk0 = (kt < 6 ? kt : kt - 6) * 64 + c8 * 8;
#pragma unroll
    for (int i = 0; i < 4; ++i)
      d[i] = *reinterpret_cast<const short8v*>(ab + (size_t)(row0 + rI[i]) * DIM + kk0);
  };
  auto loadB = [&](int kt, short8v* d) {
    int kk0 = kt * 64 + c8 * 8;
#pragma unroll
    for (int i = 0; i < 4; ++i)
      d[i] = *reinterpret_cast<const short8v*>(wpb + (size_t)(col0 + rI[i]) * 768 + kk0);
  };
  auto writeAB = [&](int p, const short8v* a, const short8v* b) {
#pragma unroll
    for (int i = 0; i < 4; ++i)
      *reinterpret_cast<short8v*>(&Abuf[p][rI[i] * LDAP + c8 * 8]) = a[i];
#pragma unroll
    for (int i = 0; i < 4; ++i)
      *reinterpret_cast<short8v*>(&Bbuf[p][rI[i] * LDAP + c8 * 8]) = b[i];
  };

  f32x4 acc[4][4];
#pragma unroll
  for (int i = 0; i < 4; ++i)
#pragma unroll
    for (int j = 0; j < 4; ++j) acc[i][j] = (f32x4){0.f, 0.f, 0.f, 0.f};

  short8v a0[4], b0[4], a1[4], b1[4];
  loadA(0, a0); loadB(0, b0);
  loadA(1, a1); loadB(1, b1);
  writeAB(0, a0, b0);
  __syncthreads();

#pragma unroll
  for (int s = 0; s < 12; ++s) {
    int p = s & 1;
    if (s < 11) {
      if (s & 1) writeAB(p ^ 1, a0, b0);
      else       writeAB(p ^ 1, a1, b1);
    }
    if (s < 10) {
      if (s & 1) { loadA(s + 2, a1); loadB(s + 2, b1); }
      else       { loadA(s + 2, a0); loadB(s + 2, b0); }
    }
#pragma unroll
    for (int ks = 0; ks < 2; ++ks) {
      int ko = ks * 32 + g * 8;
      fragT af[4], bfv[4];
#pragma unroll
      for (int mi = 0; mi < 4; ++mi)
        af[mi] = *reinterpret_cast<const fragT*>(&Abuf[p][(wr * 64 + mi * 16 + m) * LDAP + ko]);
#pragma unroll
      for (int ni = 0; ni < 4; ++ni)
        bfv[ni] = *reinterpret_cast<const fragT*>(&Bbuf[p][(wc * 64 + ni * 16 + m) * LDAP + ko]);
      __builtin_amdgcn_s_setprio(1);
#pragma unroll
      for (int mi = 0; mi < 4; ++mi)
#pragma unroll
        for (int ni = 0; ni < 4; ++ni)
          acc[mi][ni] = __builtin_amdgcn_mfma_f32_16x16x32_bf16(af[mi], bfv[ni], acc[mi][ni], 0, 0, 0);
      __builtin_amdgcn_s_setprio(0);
    }
    __syncthreads();
  }

#pragma unroll
  for (int mi = 0; mi < 4; ++mi)
#pragma unroll
    for (int ni = 0; ni < 4; ++ni) {
      int d = col0 + wc * 64 + ni * 16 + m;
#pragma unroll
      for (int r = 0; r < 4; ++r) {
        int token = row0 + wr * 64 + mi * 16 + g * 4 + r;
        out[(size_t)token * DIM + d] = x[(size_t)token * DIM + d] + acc[mi][ni][r];
      }
    }
}

extern "C" void kernel_launch(void* const* d_in, const int* in_sizes, int n_in,
                              void* d_out, int out_size, void* d_ws, size_t ws_size,
                              hipStream_t stream) {
  (void)in_sizes; (void)n_in; (void)out_size; (void)ws_size;
  const float* x = (const float*)d_in[0];
  const float* nw = (const float*)d_in[1];
  const float* we = (const float*)d_in[2];
  const float* wp = (const float*)d_in[3];
  const float* pm = (const float*)d_in[4];
  char* ws = (char*)d_ws;
  bf16* xn = (bf16*)(ws);
  bf16* qk = (bf16*)(ws + 50331648);
  bf16* gl = (bf16*)(ws + 62914560);
  bf16* gv = (bf16*)(ws + 113246208);
  bf16* at = (bf16*)(ws + 163577856);
  bf16* web = (bf16*)(ws + 163577856);  // alias: consumed before `at` is written
  bf16* wpb = (bf16*)(ws + 213909504);
  float* out = (float*)d_out;

  hipLaunchKernelGGL(conv_kernel, dim3(512), dim3(256), 0, stream, we, wp, web, wpb);
  hipLaunchKernelGGL(ln_kernel, dim3(NTOK / 4), dim3(256), 0, stream, x, nw, xn);
  hipLaunchKernelGGL(expand_db_kernel, dim3(512 * 7), dim3(256), 0, stream, xn, web, qk, gl, gv);
  hipLaunchKernelGGL(attn_mfma_kernel, dim3(NBATCH * (S_LEN / 32)), dim3(256), 0, stream, qk, gv, pm, at);
  hipLaunchKernelGGL(project_db_kernel, dim3(512 * 3), dim3(256), 0, stream, gl, at, wpb, x, out);
}

// Round 7
// 266.867 us; speedup vs baseline: 1.4668x; 1.0486x over previous
//
#include <hip/hip_runtime.h>
#include <hip/hip_bf16.h>
#include <math.h>

#define S_LEN 2048
#define NBATCH 32
#define DIM 384
#define NTOK (NBATCH * S_LEN)

typedef __hip_bfloat16 bf16;
typedef __attribute__((ext_vector_type(8))) short short8v;
typedef __attribute__((ext_vector_type(4))) float f32x4;
typedef __attribute__((ext_vector_type(2))) unsigned int uint2v;
typedef __attribute__((ext_vector_type(4))) int int4v;
typedef short8v fragT;

#define LDAP 72  // padded LDS leading dim (halfwords) — attn kernel only

__device__ __forceinline__ float bf2f(unsigned short u) {
  union { unsigned int i; float f; } c; c.i = ((unsigned int)u) << 16; return c.f;
}

// direct global->LDS DMA, 16B per lane; LDS dest = wave-uniform base + lane*16
__device__ __forceinline__ void gl16(const bf16* g, short* l) {
  __builtin_amdgcn_global_load_lds(
      (const __attribute__((address_space(1))) void*)g,
      (__attribute__((address_space(3))) void*)l, 16, 0, 0);
}

// ---------------- weight fp32 -> bf16 conversion ----------------
__global__ __launch_bounds__(256) void conv_kernel(const float* __restrict__ we,
                                                   const float* __restrict__ wp,
                                                   bf16* __restrict__ web,
                                                   bf16* __restrict__ wpb) {
  int i = blockIdx.x * 256 + threadIdx.x;
  int stride = gridDim.x * 256;
  for (int j = i; j < 1632 * 384; j += stride) web[j] = __float2bfloat16(we[j]);
  for (int j = i; j < 384 * 768; j += stride) wpb[j] = __float2bfloat16(wp[j]);
}

// ---------------- LayerNorm: x (fp32) -> xn (bf16) ----------------
__global__ __launch_bounds__(256) void ln_kernel(const float* __restrict__ x,
                                                 const float* __restrict__ nw,
                                                 bf16* __restrict__ xn) {
  int token = blockIdx.x * 4 + (threadIdx.x >> 6);
  int lane = threadIdx.x & 63;
  const float* xr = x + (size_t)token * DIM;
  float v[6];
  float s = 0.f, sq = 0.f;
#pragma unroll
  for (int j = 0; j < 6; ++j) {
    v[j] = xr[lane + j * 64];
    s += v[j];
    sq += v[j] * v[j];
  }
#pragma unroll
  for (int o = 32; o; o >>= 1) {
    s += __shfl_xor(s, o);
    sq += __shfl_xor(sq, o);
  }
  float mu = s * (1.f / DIM);
  float var = sq * (1.f / DIM) - mu * mu;
  float rs = rsqrtf(var + 1e-5f);
  bf16* xo = xn + (size_t)token * DIM;
#pragma unroll
  for (int j = 0; j < 6; ++j) {
    int c = lane + j * 64;
    xo[c] = __float2bfloat16((v[j] - mu) * rs * nw[c]);
  }
}

// ---------------- expand GEMM: global_load_lds staging (m97 structure) -----
// BM=128 x BN=256, BK=64, 6 K-steps, 4 waves (2M x 2N), single LDS buffer,
// 2 barriers/step. Linear LDS + pre-swizzled global source (chunk ^= row&7),
// ds_read applies the same XOR. XCD-swizzled flat grid 3584 = 512 x * 7 y.
__global__ __launch_bounds__(256, 2) void expand_gl_kernel(
    const bf16* __restrict__ xn, const bf16* __restrict__ web,
    bf16* __restrict__ qkb, bf16* __restrict__ gl, bf16* __restrict__ gv) {
  __shared__ short As2[128 * 64];  // 16384 B, linear
  __shared__ short Bs2[256 * 64];  // 32768 B, linear
  int t = threadIdx.x;
  int lane = t & 63, w = t >> 6;
  int wr = w >> 1, wc = w & 1;
  int m = lane & 15, g = lane >> 4;

  int bid = blockIdx.x;
  int logical = (bid & 7) * 448 + (bid >> 3);
  int xt = logical / 7, y = logical % 7;
  int row0 = xt * 128;

  int lr = lane >> 3;      // row within 8-row group
  int s8 = lane & 7;       // LDS slot this lane fills
  int cs = s8 ^ lr;        // swizzled source chunk

  const bf16* ga[4];
  const bf16* gb[8];
#pragma unroll
  for (int i = 0; i < 4; ++i) {
    int row = w * 32 + i * 8 + lr;
    ga[i] = xn + (size_t)(row0 + row) * 384 + cs * 8;
  }
#pragma unroll
  for (int i = 0; i < 8; ++i) {
    int row = w * 64 + i * 8 + lr;  // 0..255
    int brow;
    if (y == 0) brow = (row < 96) ? row : 95;  // clamp: harmless garbage
    else {
      int c0 = (y - 1) * 128, half = row >> 7, nn = row & 127;
      brow = (nn < 64) ? (96 + c0 + half * 64 + nn) : (864 + c0 + half * 64 + (nn - 64));
    }
    gb[i] = web + (size_t)brow * 384 + cs * 8;
  }
  short* la[4];
  short* lb[8];
#pragma unroll
  for (int i = 0; i < 4; ++i) la[i] = As2 + (w * 4 + i) * 512;
#pragma unroll
  for (int i = 0; i < 8; ++i) lb[i] = Bs2 + (w * 8 + i) * 512;

  f32x4 acc[4][8];
#pragma unroll
  for (int i = 0; i < 4; ++i)
#pragma unroll
    for (int j = 0; j < 8; ++j) acc[i][j] = (f32x4){0.f, 0.f, 0.f, 0.f};

#pragma unroll
  for (int kt = 0; kt < 6; ++kt) {
    __syncthreads();  // prior step's ds_reads done before overwrite
#pragma unroll
    for (int i = 0; i < 4; ++i) gl16(ga[i] + kt * 64, la[i]);
#pragma unroll
    for (int i = 0; i < 8; ++i) gl16(gb[i] + kt * 64, lb[i]);
    __syncthreads();  // compiler drains vmcnt(0) before barrier -> LDS valid
#pragma unroll
    for (int ks = 0; ks < 2; ++ks) {
      int c = ks * 4 + g;
      int cxm = c ^ (m & 7);
      fragT af[4], bf8[8];
#pragma unroll
      for (int mi = 0; mi < 4; ++mi) {
        int R = wr * 64 + mi * 16 + m;
        af[mi] = *reinterpret_cast<const fragT*>(&As2[R * 64 + cxm * 8]);
      }
#pragma unroll
      for (int ni = 0; ni < 8; ++ni) {
        int R = wc * 128 + ni * 16 + m;
        bf8[ni] = *reinterpret_cast<const fragT*>(&Bs2[R * 64 + cxm * 8]);
      }
      __builtin_amdgcn_s_setprio(1);
#pragma unroll
      for (int mi = 0; mi < 4; ++mi)
#pragma unroll
        for (int ni = 0; ni < 8; ++ni)
          acc[mi][ni] = __builtin_amdgcn_mfma_f32_16x16x32_bf16(af[mi], bf8[ni], acc[mi][ni], 0, 0, 0);
      __builtin_amdgcn_s_setprio(0);
    }
  }

  // ---- epilogue ----
  int cl = m, rg = g;
  if (y == 0) {
    if (wc == 0) {
#pragma unroll
      for (int mi = 0; mi < 4; ++mi)
#pragma unroll
        for (int ni = 0; ni < 6; ++ni) {
          int n = ni * 16 + cl;
          if (n < 96) {
#pragma unroll
            for (int r = 0; r < 4; ++r) {
              int token = row0 + wr * 64 + mi * 16 + rg * 4 + r;
              qkb[(size_t)token * 96 + n] = __float2bfloat16(acc[mi][ni][r]);
            }
          }
        }
    }
  } else {
    int c0 = (y - 1) * 128;
#pragma unroll
    for (int mi = 0; mi < 4; ++mi)
#pragma unroll
      for (int ni = 0; ni < 4; ++ni) {
        int c = c0 + wc * 64 + ni * 16 + cl;
#pragma unroll
        for (int r = 0; r < 4; ++r) {
          int token = row0 + wr * 64 + mi * 16 + rg * 4 + r;
          float lin = acc[mi][ni][r];
          float pre = acc[mi][ni + 4][r];
          float z = 0.79788456f * (pre + 0.044715f * pre * pre * pre);
          float gelu = pre * (1.f / (1.f + __expf(-2.f * z)));
          float gval = lin * gelu;
          if (c < 384)
            gl[(size_t)token * DIM + c] = __float2bfloat16(gval);
          else
            gv[(size_t)token * DIM + (c - 384)] = __float2bfloat16(gval);
        }
      }
  }
}

// ---------------- MFMA windowed causal attention (unchanged) ----------------
#define ATT_P_OFF 0
#define ATT_Q_OFF 8704
#define ATT_K_OFF 13312
#define ATT_S_OFF 31744
#define ATT_V0_OFF 8704
#define ATT_V1_OFF 36352
#define ATT_SMEM 64000

__global__ __launch_bounds__(256) void attn_mfma_kernel(
    const bf16* __restrict__ qkb, const bf16* __restrict__ gv,
    const float* __restrict__ pos_mult, bf16* __restrict__ ao) {
  __shared__ char smem[ATT_SMEM];
  bf16* P = (bf16*)(smem + ATT_P_OFF);
  bf16* Qs = (bf16*)(smem + ATT_Q_OFF);
  bf16* Ks = (bf16*)(smem + ATT_K_OFF);
  float* Ss = (float*)(smem + ATT_S_OFF);

  int t = threadIdx.x;
  int lane = t & 63;
  int w = t >> 6;
  int batch = blockIdx.x >> 6;
  int q0 = (blockIdx.x & 63) * 32;
  size_t tb = (size_t)batch * S_LEN;
  int jbase = q0 - 96;
  float cmul = log1pf(expf(pos_mult[0]));
  const float rs = 0.14433756729740643f;
  const short8v z8 = (short8v){0, 0, 0, 0, 0, 0, 0, 0};

  {
    int r = t >> 3, c = t & 7;
    short8v v = z8;
    if (c < 6) v = *reinterpret_cast<const short8v*>(qkb + (tb + q0 + r) * 96 + c * 8);
    *reinterpret_cast<short8v*>(Qs + r * LDAP + c * 8) = v;
  }
  {
    int r = t >> 1, h = t & 1;
    int j = jbase + r;
    if (j >= 0) {
      const bf16* krow = qkb + (tb + j) * 96 + 48 + h * 24;
      *reinterpret_cast<short8v*>(Ks + r * LDAP + h * 24) = *reinterpret_cast<const short8v*>(krow);
      *reinterpret_cast<short8v*>(Ks + r * LDAP + h * 24 + 8) = *reinterpret_cast<const short8v*>(krow + 8);
      *reinterpret_cast<short8v*>(Ks + r * LDAP + h * 24 + 16) = *reinterpret_cast<const short8v*>(krow + 16);
    } else {
      *reinterpret_cast<short8v*>(Ks + r * LDAP + h * 24) = z8;
      *reinterpret_cast<short8v*>(Ks + r * LDAP + h * 24 + 8) = z8;
      *reinterpret_cast<short8v*>(Ks + r * LDAP + h * 24 + 16) = z8;
    }
    if (h == 1) {
      *reinterpret_cast<short8v*>(Ks + r * LDAP + 48) = z8;
      *reinterpret_cast<short8v*>(Ks + r * LDAP + 56) = z8;
    }
  }
  __syncthreads();

  int m = lane & 15, g = lane >> 4;

  {
    f32x4 sacc[2][2];
#pragma unroll
    for (int mi = 0; mi < 2; ++mi)
#pragma unroll
      for (int ni = 0; ni < 2; ++ni) sacc[mi][ni] = (f32x4){0.f, 0.f, 0.f, 0.f};
#pragma unroll
    for (int ks = 0; ks < 2; ++ks) {
      int ko = ks * 32 + g * 8;
      fragT aq[2], bk[2];
#pragma unroll
      for (int mi = 0; mi < 2; ++mi)
        aq[mi] = *reinterpret_cast<const fragT*>(Qs + (mi * 16 + m) * LDAP + ko);
#pragma unroll
      for (int ni = 0; ni < 2; ++ni)
        bk[ni] = *reinterpret_cast<const fragT*>(Ks + (w * 32 + ni * 16 + m) * LDAP + ko);
#pragma unroll
      for (int mi = 0; mi < 2; ++mi)
#pragma unroll
        for (int ni = 0; ni < 2; ++ni)
          sacc[mi][ni] = __builtin_amdgcn_mfma_f32_16x16x32_bf16(aq[mi], bk[ni], sacc[mi][ni], 0, 0, 0);
    }
#pragma unroll
    for (int mi = 0; mi < 2; ++mi)
#pragma unroll
      for (int ni = 0; ni < 2; ++ni)
#pragma unroll
        for (int r = 0; r < 4; ++r) {
          int q = mi * 16 + g * 4 + r;
          int key = w * 32 + ni * 16 + m;
          int gi = q0 + q, gj = jbase + key;
          float s = (gj >= 0 && gj <= gi)
                        ? sacc[mi][ni][r] * rs + cmul * (float)(gj - gi)
                        : -INFINITY;
          Ss[q * 132 + key] = s;
        }
  }
  __syncthreads();

  auto stageV = [&](int c, unsigned bufoff) {
    int j = t >> 3;
    int c8 = t & 7;
    int gj = jbase + c * 32 + j;
    bf16* vb = (bf16*)(smem + bufoff);
    const bf16* vrow = gv + (tb + gj) * (size_t)DIM;
#pragma unroll
    for (int it = 0; it < 6; ++it) {
      int dj = c8 + it * 8;
      int d = dj * 8;
      short8v v = z8;
      if (gj >= 0) v = *reinterpret_cast<const short8v*>(vrow + d);
      *reinterpret_cast<short8v*>(vb + ((j >> 2) * 24 + (d >> 4)) * LDAP + (j & 3) * 16 + (d & 15)) = v;
    }
  };

  {
    int sq = t >> 3, sl = t & 7;
    union { float4 f4[4]; float f[16]; } su;
#pragma unroll
    for (int u = 0; u < 4; ++u)
      su.f4[u] = *reinterpret_cast<const float4*>(Ss + sq * 132 + sl * 16 + u * 4);
    __syncthreads();
    float mx = -INFINITY;
#pragma unroll
    for (int e = 0; e < 16; ++e) mx = fmaxf(mx, su.f[e]);
    mx = fmaxf(mx, __shfl_xor(mx, 1));
    mx = fmaxf(mx, __shfl_xor(mx, 2));
    mx = fmaxf(mx, __shfl_xor(mx, 4));
    float pv[16];
    float sum = 0.f;
#pragma unroll
    for (int e = 0; e < 16; ++e) {
      pv[e] = expf(su.f[e] - mx);
      sum += pv[e];
    }
    sum += __shfl_xor(sum, 1);
    sum += __shfl_xor(sum, 2);
    sum += __shfl_xor(sum, 4);
    float inv = 1.f / sum;
    union { bf16 b[16]; short8v s[2]; } pk;
#pragma unroll
    for (int e = 0; e < 16; ++e) pk.b[e] = __float2bfloat16(pv[e] * inv);
    bf16* pr = P + sq * 136 + sl * 16;
    *reinterpret_cast<short8v*>(pr) = pk.s[0];
    *reinterpret_cast<short8v*>(pr + 8) = pk.s[1];
  }
  stageV(0, ATT_V0_OFF);
  __syncthreads();

  f32x4 oacc[2][6];
#pragma unroll
  for (int mi = 0; mi < 2; ++mi)
#pragma unroll
    for (int nt = 0; nt < 6; ++nt) oacc[mi][nt] = (f32x4){0.f, 0.f, 0.f, 0.f};

  unsigned sbase = (unsigned)(size_t)(&smem[0]);
  unsigned lanebase = (unsigned)(((48 * g + 6 * w) * LDAP + m) * 2);

  for (int c = 0; c < 4; ++c) {
    unsigned vaddr = sbase + ((c & 1) ? ATT_V1_OFF : ATT_V0_OFF) + lanebase;
    fragT pa0 = *reinterpret_cast<const fragT*>(P + m * 136 + c * 32 + g * 8);
    fragT pa1 = *reinterpret_cast<const fragT*>(P + (16 + m) * 136 + c * 32 + g * 8);
    uint2v trr[12];
#pragma unroll
    for (int nt = 0; nt < 6; ++nt) {
      asm volatile("ds_read_b64_tr_b16 %0, %1" : "=v"(trr[2 * nt]) : "v"(vaddr + nt * 144));
      asm volatile("ds_read_b64_tr_b16 %0, %1" : "=v"(trr[2 * nt + 1]) : "v"(vaddr + nt * 144 + 3456));
    }
    asm volatile("s_waitcnt lgkmcnt(0)" ::: "memory");
    __builtin_amdgcn_sched_barrier(0);
    if (c < 3) stageV(c + 1, (c & 1) ? ATT_V0_OFF : ATT_V1_OFF);
#pragma unroll
    for (int nt = 0; nt < 6; ++nt) {
      union { int4v i4; fragT f; } u;
      u.i4 = (int4v){(int)trr[2 * nt].x, (int)trr[2 * nt].y,
                     (int)trr[2 * nt + 1].x, (int)trr[2 * nt + 1].y};
      oacc[0][nt] = __builtin_amdgcn_mfma_f32_16x16x32_bf16(pa0, u.f, oacc[0][nt], 0, 0, 0);
      oacc[1][nt] = __builtin_amdgcn_mfma_f32_16x16x32_bf16(pa1, u.f, oacc[1][nt], 0, 0, 0);
    }
    __syncthreads();
  }

#pragma unroll
  for (int mi = 0; mi < 2; ++mi)
#pragma unroll
    for (int nt = 0; nt < 6; ++nt) {
#pragma unroll
      for (int r = 0; r < 4; ++r) {
        int q = mi * 16 + g * 4 + r;
        int d = w * 96 + nt * 16 + m;
        ao[(tb + q0 + q) * (size_t)DIM + d] = __float2bfloat16(oacc[mi][nt][r]);
      }
    }
}

// ---------------- project GEMM: global_load_lds staging + residual --------
// BM=128 x BN=128, K=768 ([gl | attn]), BK=64, 12 steps, single buffer,
// 2 barriers/step, linear LDS + pre-swizzled source. XCD-swizzled grid 1536.
__global__ __launch_bounds__(256, 2) void project_gl_kernel(
    const bf16* __restrict__ gl, const bf16* __restrict__ at,
    const bf16* __restrict__ wpb, const float* __restrict__ x,
    float* __restrict__ out) {
  __shared__ short As2[128 * 64];  // 16384 B
  __shared__ short Bs2[128 * 64];  // 16384 B
  int t = threadIdx.x;
  int bid = blockIdx.x;
  int logical = (bid & 7) * 192 + (bid >> 3);
  int row0 = (logical / 3) * 128;
  int col0 = (logical % 3) * 128;
  int lane = t & 63, w = t >> 6;
  int wr = w >> 1, wc = w & 1;
  int m = lane & 15, g = lane >> 4;

  int lr = lane >> 3;
  int s8 = lane & 7;
  int cs = s8 ^ lr;

  size_t aoff[4];
  const bf16* gbp[4];
#pragma unroll
  for (int i = 0; i < 4; ++i) {
    int row = w * 32 + i * 8 + lr;
    aoff[i] = (size_t)(row0 + row) * 384 + cs * 8;
    gbp[i] = wpb + (size_t)(col0 + row) * 768 + cs * 8;
  }
  short* la[4];
  short* lb[4];
#pragma unroll
  for (int i = 0; i < 4; ++i) {
    la[i] = As2 + (w * 4 + i) * 512;
    lb[i] = Bs2 + (w * 4 + i) * 512;
  }

  f32x4 acc[4][4];
#pragma unroll
  for (int i = 0; i < 4; ++i)
#pragma unroll
    for (int j = 0; j < 4; ++j) acc[i][j] = (f32x4){0.f, 0.f, 0.f, 0.f};

#pragma unroll
  for (int kt = 0; kt < 12; ++kt) {
    const bf16* ab = (kt < 6) ? gl : at;
    int kk = (kt < 6 ? kt : kt - 6) * 64;
    __syncthreads();
#pragma unroll
    for (int i = 0; i < 4; ++i) gl16(ab + aoff[i] + kk, la[i]);
#pragma unroll
    for (int i = 0; i < 4; ++i) gl16(gbp[i] + kt * 64, lb[i]);
    __syncthreads();
#pragma unroll
    for (int ks = 0; ks < 2; ++ks) {
      int c = ks * 4 + g;
      int cxm = c ^ (m & 7);
      fragT af[4], bfv[4];
#pragma unroll
      for (int mi = 0; mi < 4; ++mi) {
        int R = wr * 64 + mi * 16 + m;
        af[mi] = *reinterpret_cast<const fragT*>(&As2[R * 64 + cxm * 8]);
      }
#pragma unroll
      for (int ni = 0; ni < 4; ++ni) {
        int R = wc * 64 + ni * 16 + m;
        bfv[ni] = *reinterpret_cast<const fragT*>(&Bs2[R * 64 + cxm * 8]);
      }
      __builtin_amdgcn_s_setprio(1);
#pragma unroll
      for (int mi = 0; mi < 4; ++mi)
#pragma unroll
        for (int ni = 0; ni < 4; ++ni)
          acc[mi][ni] = __builtin_amdgcn_mfma_f32_16x16x32_bf16(af[mi], bfv[ni], acc[mi][ni], 0, 0, 0);
      __builtin_amdgcn_s_setprio(0);
    }
  }

#pragma unroll
  for (int mi = 0; mi < 4; ++mi)
#pragma unroll
    for (int ni = 0; ni < 4; ++ni) {
      int d = col0 + wc * 64 + ni * 16 + m;
#pragma unroll
      for (int r = 0; r < 4; ++r) {
        int token = row0 + wr * 64 + mi * 16 + g * 4 + r;
        out[(size_t)token * DIM + d] = x[(size_t)token * DIM + d] + acc[mi][ni][r];
      }
    }
}

extern "C" void kernel_launch(void* const* d_in, const int* in_sizes, int n_in,
                              void* d_out, int out_size, void* d_ws, size_t ws_size,
                              hipStream_t stream) {
  (void)in_sizes; (void)n_in; (void)out_size; (void)ws_size;
  const float* x = (const float*)d_in[0];
  const float* nw = (const float*)d_in[1];
  const float* we = (const float*)d_in[2];
  const float* wp = (const float*)d_in[3];
  const float* pm = (const float*)d_in[4];
  char* ws = (char*)d_ws;
  bf16* xn = (bf16*)(ws);
  bf16* qk = (bf16*)(ws + 50331648);
  bf16* gl = (bf16*)(ws + 62914560);
  bf16* gv = (bf16*)(ws + 113246208);
  bf16* at = (bf16*)(ws + 163577856);
  bf16* web = (bf16*)(ws + 163577856);  // alias: consumed before `at` is written
  bf16* wpb = (bf16*)(ws + 213909504);
  float* out = (float*)d_out;

  hipLaunchKernelGGL(conv_kernel, dim3(512), dim3(256), 0, stream, we, wp, web, wpb);
  hipLaunchKernelGGL(ln_kernel, dim3(NTOK / 4), dim3(256), 0, stream, x, nw, xn);
  hipLaunchKernelGGL(expand_gl_kernel, dim3(512 * 7), dim3(256), 0, stream, xn, web, qk, gl, gv);
  hipLaunchKernelGGL(attn_mfma_kernel, dim3(NBATCH * (S_LEN / 32)), dim3(256), 0, stream, qk, gv, pm, at);
  hipLaunchKernelGGL(project_gl_kernel, dim3(512 * 3), dim3(256), 0, stream, gl, at, wpb, x, out);
}

// Round 8
// 254.777 us; speedup vs baseline: 1.5364x; 1.0475x over previous
//
#include <hip/hip_runtime.h>
#include <hip/hip_bf16.h>
#include <math.h>

#define S_LEN 2048
#define NBATCH 32
#define DIM 384
#define NTOK (NBATCH * S_LEN)

typedef __hip_bfloat16 bf16;
typedef __attribute__((ext_vector_type(8))) short short8v;
typedef __attribute__((ext_vector_type(4))) float f32x4;
typedef __attribute__((ext_vector_type(2))) unsigned int uint2v;
typedef __attribute__((ext_vector_type(4))) int int4v;
typedef short8v fragT;

#define LDAP 72  // padded LDS leading dim (halfwords) — attn kernel only

__device__ __forceinline__ float bf2f(unsigned short u) {
  union { unsigned int i; float f; } c; c.i = ((unsigned int)u) << 16; return c.f;
}

// direct global->LDS DMA, 16B per lane; LDS dest = wave-uniform base + lane*16
__device__ __forceinline__ void gl16(const bf16* g, short* l) {
  __builtin_amdgcn_global_load_lds(
      (const __attribute__((address_space(1))) void*)g,
      (__attribute__((address_space(3))) void*)l, 16, 0, 0);
}

// ---------------- weight fp32 -> bf16 conversion ----------------
__global__ __launch_bounds__(256) void conv_kernel(const float* __restrict__ we,
                                                   const float* __restrict__ wp,
                                                   bf16* __restrict__ web,
                                                   bf16* __restrict__ wpb) {
  int i = blockIdx.x * 256 + threadIdx.x;
  int stride = gridDim.x * 256;
  for (int j = i; j < 1632 * 384; j += stride) web[j] = __float2bfloat16(we[j]);
  for (int j = i; j < 384 * 768; j += stride) wpb[j] = __float2bfloat16(wp[j]);
}

// ---------------- LayerNorm: x (fp32) -> xn (bf16) ----------------
__global__ __launch_bounds__(256) void ln_kernel(const float* __restrict__ x,
                                                 const float* __restrict__ nw,
                                                 bf16* __restrict__ xn) {
  int token = blockIdx.x * 4 + (threadIdx.x >> 6);
  int lane = threadIdx.x & 63;
  const float* xr = x + (size_t)token * DIM;
  float v[6];
  float s = 0.f, sq = 0.f;
#pragma unroll
  for (int j = 0; j < 6; ++j) {
    v[j] = xr[lane + j * 64];
    s += v[j];
    sq += v[j] * v[j];
  }
#pragma unroll
  for (int o = 32; o; o >>= 1) {
    s += __shfl_xor(s, o);
    sq += __shfl_xor(sq, o);
  }
  float mu = s * (1.f / DIM);
  float var = sq * (1.f / DIM) - mu * mu;
  float rs = rsqrtf(var + 1e-5f);
  bf16* xo = xn + (size_t)token * DIM;
#pragma unroll
  for (int j = 0; j < 6; ++j) {
    int c = lane + j * 64;
    xo[c] = __float2bfloat16((v[j] - mu) * rs * nw[c]);
  }
}

// ---------------- expand GEMM: gload_lds staging, 4 blocks/CU --------------
// BM=128 x BN=128, BK=64, 6 K-steps, 4 waves (2M x 2N), 32 KB LDS single buf,
// 2 barriers/step. Linear LDS + pre-swizzled source (chunk ^= row&7).
// Grid 6656 = 512 x * 13 y, XCD-swizzled y-inner (A-tile L2-hot).
// y=0: qk cols 0..95. y=1..12: B rows interleaved in 32-row quarters
// [linLo|preLo|linHi|preHi] so each wave holds matching lin/pre pairs.
__global__ __launch_bounds__(256, 4) void expand_gl_kernel(
    const bf16* __restrict__ xn, const bf16* __restrict__ web,
    bf16* __restrict__ qkb, bf16* __restrict__ gl, bf16* __restrict__ gv) {
  __shared__ short As2[128 * 64];  // 16384 B, linear
  __shared__ short Bs2[128 * 64];  // 16384 B, linear
  int t = threadIdx.x;
  int lane = t & 63, w = t >> 6;
  int wr = w >> 1, wc = w & 1;
  int m = lane & 15, g = lane >> 4;

  int bid = blockIdx.x;
  int logical = (bid & 7) * 832 + (bid >> 3);
  int xt = logical / 13, y = logical % 13;
  int row0 = xt * 128;

  int lr = lane >> 3;      // row within 8-row group
  int s8 = lane & 7;       // LDS slot this lane fills
  int cs = s8 ^ lr;        // swizzled source chunk

  const bf16* ga[4];
  const bf16* gb[4];
#pragma unroll
  for (int i = 0; i < 4; ++i) {
    int row = w * 32 + i * 8 + lr;
    ga[i] = xn + (size_t)(row0 + row) * 384 + cs * 8;
    int brow;
    if (y == 0) brow = (row < 96) ? row : 95;  // clamp: harmless garbage
    else {
      int q = row >> 5, nn = row & 31;
      int base = (y - 1) * 64 + (q >> 1) * 32 + nn;
      brow = (q & 1) ? (864 + base) : (96 + base);
    }
    gb[i] = web + (size_t)brow * 384 + cs * 8;
  }
  short* la[4];
  short* lb[4];
#pragma unroll
  for (int i = 0; i < 4; ++i) {
    la[i] = As2 + (w * 4 + i) * 512;
    lb[i] = Bs2 + (w * 4 + i) * 512;
  }

  f32x4 acc[4][4];
#pragma unroll
  for (int i = 0; i < 4; ++i)
#pragma unroll
    for (int j = 0; j < 4; ++j) acc[i][j] = (f32x4){0.f, 0.f, 0.f, 0.f};

#pragma unroll
  for (int kt = 0; kt < 6; ++kt) {
    __syncthreads();  // prior step's ds_reads done before overwrite
#pragma unroll
    for (int i = 0; i < 4; ++i) gl16(ga[i] + kt * 64, la[i]);
#pragma unroll
    for (int i = 0; i < 4; ++i) gl16(gb[i] + kt * 64, lb[i]);
    __syncthreads();  // vmcnt(0) drained before barrier -> LDS valid
#pragma unroll
    for (int ks = 0; ks < 2; ++ks) {
      int c = ks * 4 + g;
      int cxm = c ^ (m & 7);
      fragT af[4], bfv[4];
#pragma unroll
      for (int mi = 0; mi < 4; ++mi) {
        int R = wr * 64 + mi * 16 + m;
        af[mi] = *reinterpret_cast<const fragT*>(&As2[R * 64 + cxm * 8]);
      }
#pragma unroll
      for (int ni = 0; ni < 4; ++ni) {
        int R = wc * 64 + ni * 16 + m;
        bfv[ni] = *reinterpret_cast<const fragT*>(&Bs2[R * 64 + cxm * 8]);
      }
      __builtin_amdgcn_s_setprio(1);
#pragma unroll
      for (int mi = 0; mi < 4; ++mi)
#pragma unroll
        for (int ni = 0; ni < 4; ++ni)
          acc[mi][ni] = __builtin_amdgcn_mfma_f32_16x16x32_bf16(af[mi], bfv[ni], acc[mi][ni], 0, 0, 0);
      __builtin_amdgcn_s_setprio(0);
    }
  }

  // ---- epilogue ----
  if (y == 0) {
#pragma unroll
    for (int mi = 0; mi < 4; ++mi)
#pragma unroll
      for (int ni = 0; ni < 4; ++ni) {
        int n = wc * 64 + ni * 16 + m;
        if (n < 96) {
#pragma unroll
          for (int r = 0; r < 4; ++r) {
            int token = row0 + wr * 64 + mi * 16 + g * 4 + r;
            qkb[(size_t)token * 96 + n] = __float2bfloat16(acc[mi][ni][r]);
          }
        }
      }
  } else {
#pragma unroll
    for (int mi = 0; mi < 4; ++mi)
#pragma unroll
      for (int ni = 0; ni < 2; ++ni) {
        int c = (y - 1) * 64 + wc * 32 + ni * 16 + m;  // geglu col 0..767
#pragma unroll
        for (int r = 0; r < 4; ++r) {
          int token = row0 + wr * 64 + mi * 16 + g * 4 + r;
          float lin = acc[mi][ni][r];
          float pre = acc[mi][ni + 2][r];
          float z = 0.79788456f * (pre + 0.044715f * pre * pre * pre);
          float gelu = pre * (1.f / (1.f + __expf(-2.f * z)));
          float gval = lin * gelu;
          if (c < 384)
            gl[(size_t)token * DIM + c] = __float2bfloat16(gval);
          else
            gv[(size_t)token * DIM + (c - 384)] = __float2bfloat16(gval);
        }
      }
  }
}

// ---------------- MFMA windowed causal attention (unchanged) ----------------
#define ATT_P_OFF 0
#define ATT_Q_OFF 8704
#define ATT_K_OFF 13312
#define ATT_S_OFF 31744
#define ATT_V0_OFF 8704
#define ATT_V1_OFF 36352
#define ATT_SMEM 64000

__global__ __launch_bounds__(256) void attn_mfma_kernel(
    const bf16* __restrict__ qkb, const bf16* __restrict__ gv,
    const float* __restrict__ pos_mult, bf16* __restrict__ ao) {
  __shared__ char smem[ATT_SMEM];
  bf16* P = (bf16*)(smem + ATT_P_OFF);
  bf16* Qs = (bf16*)(smem + ATT_Q_OFF);
  bf16* Ks = (bf16*)(smem + ATT_K_OFF);
  float* Ss = (float*)(smem + ATT_S_OFF);

  int t = threadIdx.x;
  int lane = t & 63;
  int w = t >> 6;
  int batch = blockIdx.x >> 6;
  int q0 = (blockIdx.x & 63) * 32;
  size_t tb = (size_t)batch * S_LEN;
  int jbase = q0 - 96;
  float cmul = log1pf(expf(pos_mult[0]));
  const float rs = 0.14433756729740643f;
  const short8v z8 = (short8v){0, 0, 0, 0, 0, 0, 0, 0};

  {
    int r = t >> 3, c = t & 7;
    short8v v = z8;
    if (c < 6) v = *reinterpret_cast<const short8v*>(qkb + (tb + q0 + r) * 96 + c * 8);
    *reinterpret_cast<short8v*>(Qs + r * LDAP + c * 8) = v;
  }
  {
    int r = t >> 1, h = t & 1;
    int j = jbase + r;
    if (j >= 0) {
      const bf16* krow = qkb + (tb + j) * 96 + 48 + h * 24;
      *reinterpret_cast<short8v*>(Ks + r * LDAP + h * 24) = *reinterpret_cast<const short8v*>(krow);
      *reinterpret_cast<short8v*>(Ks + r * LDAP + h * 24 + 8) = *reinterpret_cast<const short8v*>(krow + 8);
      *reinterpret_cast<short8v*>(Ks + r * LDAP + h * 24 + 16) = *reinterpret_cast<const short8v*>(krow + 16);
    } else {
      *reinterpret_cast<short8v*>(Ks + r * LDAP + h * 24) = z8;
      *reinterpret_cast<short8v*>(Ks + r * LDAP + h * 24 + 8) = z8;
      *reinterpret_cast<short8v*>(Ks + r * LDAP + h * 24 + 16) = z8;
    }
    if (h == 1) {
      *reinterpret_cast<short8v*>(Ks + r * LDAP + 48) = z8;
      *reinterpret_cast<short8v*>(Ks + r * LDAP + 56) = z8;
    }
  }
  __syncthreads();

  int m = lane & 15, g = lane >> 4;

  {
    f32x4 sacc[2][2];
#pragma unroll
    for (int mi = 0; mi < 2; ++mi)
#pragma unroll
      for (int ni = 0; ni < 2; ++ni) sacc[mi][ni] = (f32x4){0.f, 0.f, 0.f, 0.f};
#pragma unroll
    for (int ks = 0; ks < 2; ++ks) {
      int ko = ks * 32 + g * 8;
      fragT aq[2], bk[2];
#pragma unroll
      for (int mi = 0; mi < 2; ++mi)
        aq[mi] = *reinterpret_cast<const fragT*>(Qs + (mi * 16 + m) * LDAP + ko);
#pragma unroll
      for (int ni = 0; ni < 2; ++ni)
        bk[ni] = *reinterpret_cast<const fragT*>(Ks + (w * 32 + ni * 16 + m) * LDAP + ko);
#pragma unroll
      for (int mi = 0; mi < 2; ++mi)
#pragma unroll
        for (int ni = 0; ni < 2; ++ni)
          sacc[mi][ni] = __builtin_amdgcn_mfma_f32_16x16x32_bf16(aq[mi], bk[ni], sacc[mi][ni], 0, 0, 0);
    }
#pragma unroll
    for (int mi = 0; mi < 2; ++mi)
#pragma unroll
      for (int ni = 0; ni < 2; ++ni)
#pragma unroll
        for (int r = 0; r < 4; ++r) {
          int q = mi * 16 + g * 4 + r;
          int key = w * 32 + ni * 16 + m;
          int gi = q0 + q, gj = jbase + key;
          float s = (gj >= 0 && gj <= gi)
                        ? sacc[mi][ni][r] * rs + cmul * (float)(gj - gi)
                        : -INFINITY;
          Ss[q * 132 + key] = s;
        }
  }
  __syncthreads();

  auto stageV = [&](int c, unsigned bufoff) {
    int j = t >> 3;
    int c8 = t & 7;
    int gj = jbase + c * 32 + j;
    bf16* vb = (bf16*)(smem + bufoff);
    const bf16* vrow = gv + (tb + gj) * (size_t)DIM;
#pragma unroll
    for (int it = 0; it < 6; ++it) {
      int dj = c8 + it * 8;
      int d = dj * 8;
      short8v v = z8;
      if (gj >= 0) v = *reinterpret_cast<const short8v*>(vrow + d);
      *reinterpret_cast<short8v*>(vb + ((j >> 2) * 24 + (d >> 4)) * LDAP + (j & 3) * 16 + (d & 15)) = v;
    }
  };

  {
    int sq = t >> 3, sl = t & 7;
    union { float4 f4[4]; float f[16]; } su;
#pragma unroll
    for (int u = 0; u < 4; ++u)
      su.f4[u] = *reinterpret_cast<const float4*>(Ss + sq * 132 + sl * 16 + u * 4);
    __syncthreads();
    float mx = -INFINITY;
#pragma unroll
    for (int e = 0; e < 16; ++e) mx = fmaxf(mx, su.f[e]);
    mx = fmaxf(mx, __shfl_xor(mx, 1));
    mx = fmaxf(mx, __shfl_xor(mx, 2));
    mx = fmaxf(mx, __shfl_xor(mx, 4));
    float pv[16];
    float sum = 0.f;
#pragma unroll
    for (int e = 0; e < 16; ++e) {
      pv[e] = expf(su.f[e] - mx);
      sum += pv[e];
    }
    sum += __shfl_xor(sum, 1);
    sum += __shfl_xor(sum, 2);
    sum += __shfl_xor(sum, 4);
    float inv = 1.f / sum;
    union { bf16 b[16]; short8v s[2]; } pk;
#pragma unroll
    for (int e = 0; e < 16; ++e) pk.b[e] = __float2bfloat16(pv[e] * inv);
    bf16* pr = P + sq * 136 + sl * 16;
    *reinterpret_cast<short8v*>(pr) = pk.s[0];
    *reinterpret_cast<short8v*>(pr + 8) = pk.s[1];
  }
  stageV(0, ATT_V0_OFF);
  __syncthreads();

  f32x4 oacc[2][6];
#pragma unroll
  for (int mi = 0; mi < 2; ++mi)
#pragma unroll
    for (int nt = 0; nt < 6; ++nt) oacc[mi][nt] = (f32x4){0.f, 0.f, 0.f, 0.f};

  unsigned sbase = (unsigned)(size_t)(&smem[0]);
  unsigned lanebase = (unsigned)(((48 * g + 6 * w) * LDAP + m) * 2);

  for (int c = 0; c < 4; ++c) {
    unsigned vaddr = sbase + ((c & 1) ? ATT_V1_OFF : ATT_V0_OFF) + lanebase;
    fragT pa0 = *reinterpret_cast<const fragT*>(P + m * 136 + c * 32 + g * 8);
    fragT pa1 = *reinterpret_cast<const fragT*>(P + (16 + m) * 136 + c * 32 + g * 8);
    uint2v trr[12];
#pragma unroll
    for (int nt = 0; nt < 6; ++nt) {
      asm volatile("ds_read_b64_tr_b16 %0, %1" : "=v"(trr[2 * nt]) : "v"(vaddr + nt * 144));
      asm volatile("ds_read_b64_tr_b16 %0, %1" : "=v"(trr[2 * nt + 1]) : "v"(vaddr + nt * 144 + 3456));
    }
    asm volatile("s_waitcnt lgkmcnt(0)" ::: "memory");
    __builtin_amdgcn_sched_barrier(0);
    if (c < 3) stageV(c + 1, (c & 1) ? ATT_V0_OFF : ATT_V1_OFF);
#pragma unroll
    for (int nt = 0; nt < 6; ++nt) {
      union { int4v i4; fragT f; } u;
      u.i4 = (int4v){(int)trr[2 * nt].x, (int)trr[2 * nt].y,
                     (int)trr[2 * nt + 1].x, (int)trr[2 * nt + 1].y};
      oacc[0][nt] = __builtin_amdgcn_mfma_f32_16x16x32_bf16(pa0, u.f, oacc[0][nt], 0, 0, 0);
      oacc[1][nt] = __builtin_amdgcn_mfma_f32_16x16x32_bf16(pa1, u.f, oacc[1][nt], 0, 0, 0);
    }
    __syncthreads();
  }

#pragma unroll
  for (int mi = 0; mi < 2; ++mi)
#pragma unroll
    for (int nt = 0; nt < 6; ++nt) {
#pragma unroll
      for (int r = 0; r < 4; ++r) {
        int q = mi * 16 + g * 4 + r;
        int d = w * 96 + nt * 16 + m;
        ao[(tb + q0 + q) * (size_t)DIM + d] = __float2bfloat16(oacc[mi][nt][r]);
      }
    }
}

// ---------------- project GEMM: gload_lds staging + residual, 4 blocks/CU --
__global__ __launch_bounds__(256, 4) void project_gl_kernel(
    const bf16* __restrict__ gl, const bf16* __restrict__ at,
    const bf16* __restrict__ wpb, const float* __restrict__ x,
    float* __restrict__ out) {
  __shared__ short As2[128 * 64];  // 16384 B
  __shared__ short Bs2[128 * 64];  // 16384 B
  int t = threadIdx.x;
  int bid = blockIdx.x;
  int logical = (bid & 7) * 192 + (bid >> 3);
  int row0 = (logical / 3) * 128;
  int col0 = (logical % 3) * 128;
  int lane = t & 63, w = t >> 6;
  int wr = w >> 1, wc = w & 1;
  int m = lane & 15, g = lane >> 4;

  int lr = lane >> 3;
  int s8 = lane & 7;
  int cs = s8 ^ lr;

  size_t aoff[4];
  const bf16* gbp[4];
#pragma unroll
  for (int i = 0; i < 4; ++i) {
    int row = w * 32 + i * 8 + lr;
    aoff[i] = (size_t)(row0 + row) * 384 + cs * 8;
    gbp[i] = wpb + (size_t)(col0 + row) * 768 + cs * 8;
  }
  short* la[4];
  short* lb[4];
#pragma unroll
  for (int i = 0; i < 4; ++i) {
    la[i] = As2 + (w * 4 + i) * 512;
    lb[i] = Bs2 + (w * 4 + i) * 512;
  }

  f32x4 acc[4][4];
#pragma unroll
  for (int i = 0; i < 4; ++i)
#pragma unroll
    for (int j = 0; j < 4; ++j) acc[i][j] = (f32x4){0.f, 0.f, 0.f, 0.f};

#pragma unroll
  for (int kt = 0; kt < 12; ++kt) {
    const bf16* ab = (kt < 6) ? gl : at;
    int kk = (kt < 6 ? kt : kt - 6) * 64;
    __syncthreads();
#pragma unroll
    for (int i = 0; i < 4; ++i) gl16(ab + aoff[i] + kk, la[i]);
#pragma unroll
    for (int i = 0; i < 4; ++i) gl16(gbp[i] + kt * 64, lb[i]);
    __syncthreads();
#pragma unroll
    for (int ks = 0; ks < 2; ++ks) {
      int c = ks * 4 + g;
      int cxm = c ^ (m & 7);
      fragT af[4], bfv[4];
#pragma unroll
      for (int mi = 0; mi < 4; ++mi) {
        int R = wr * 64 + mi * 16 + m;
        af[mi] = *reinterpret_cast<const fragT*>(&As2[R * 64 + cxm * 8]);
      }
#pragma unroll
      for (int ni = 0; ni < 4; ++ni) {
        int R = wc * 64 + ni * 16 + m;
        bfv[ni] = *reinterpret_cast<const fragT*>(&Bs2[R * 64 + cxm * 8]);
      }
      __builtin_amdgcn_s_setprio(1);
#pragma unroll
      for (int mi = 0; mi < 4; ++mi)
#pragma unroll
        for (int ni = 0; ni < 4; ++ni)
          acc[mi][ni] = __builtin_amdgcn_mfma_f32_16x16x32_bf16(af[mi], bfv[ni], acc[mi][ni], 0, 0, 0);
      __builtin_amdgcn_s_setprio(0);
    }
  }

#pragma unroll
  for (int mi = 0; mi < 4; ++mi)
#pragma unroll
    for (int ni = 0; ni < 4; ++ni) {
      int d = col0 + wc * 64 + ni * 16 + m;
#pragma unroll
      for (int r = 0; r < 4; ++r) {
        int token = row0 + wr * 64 + mi * 16 + g * 4 + r;
        out[(size_t)token * DIM + d] = x[(size_t)token * DIM + d] + acc[mi][ni][r];
      }
    }
}

extern "C" void kernel_launch(void* const* d_in, const int* in_sizes, int n_in,
                              void* d_out, int out_size, void* d_ws, size_t ws_size,
                              hipStream_t stream) {
  (void)in_sizes; (void)n_in; (void)out_size; (void)ws_size;
  const float* x = (const float*)d_in[0];
  const float* nw = (const float*)d_in[1];
  const float* we = (const float*)d_in[2];
  const float* wp = (const float*)d_in[3];
  const float* pm = (const float*)d_in[4];
  char* ws = (char*)d_ws;
  bf16* xn = (bf16*)(ws);
  bf16* qk = (bf16*)(ws + 50331648);
  bf16* gl = (bf16*)(ws + 62914560);
  bf16* gv = (bf16*)(ws + 113246208);
  bf16* at = (bf16*)(ws + 163577856);
  bf16* web = (bf16*)(ws + 163577856);  // alias: consumed before `at` is written
  bf16* wpb = (bf16*)(ws + 213909504);
  float* out = (float*)d_out;

  hipLaunchKernelGGL(conv_kernel, dim3(512), dim3(256), 0, stream, we, wp, web, wpb);
  hipLaunchKernelGGL(ln_kernel, dim3(NTOK / 4), dim3(256), 0, stream, x, nw, xn);
  hipLaunchKernelGGL(expand_gl_kernel, dim3(512 * 13), dim3(256), 0, stream, xn, web, qk, gl, gv);
  hipLaunchKernelGGL(attn_mfma_kernel, dim3(NBATCH * (S_LEN / 32)), dim3(256), 0, stream, qk, gv, pm, at);
  hipLaunchKernelGGL(project_gl_kernel, dim3(512 * 3), dim3(256), 0, stream, gl, at, wpb, x, out);
}